// Round 5
// baseline (16764.159 us; speedup 1.0000x reference)
//
#include <hip/hip_runtime.h>
#include <cstdint>

#define BB 2
#define NN 1024
#define FF 2048
#define CC 80
#define C2 160
#define NB_ 15
#define ROWS_X (BB*FF)   /* 4096 */
#define ROWS_Y (BB*NN)   /* 2048 */

// ---------------- conv1: v = in@W0 + (L@in)@W1 + b, + v-stats partials (128 slots) ----------------
__global__ __launch_bounds__(256) void k_conv1(
    const float* __restrict__ inp, const float* __restrict__ L,
    const float* __restrict__ W0, const float* __restrict__ W1,
    const float* __restrict__ bias, float* __restrict__ v,
    float* __restrict__ vstat)
{
  int bx = blockIdx.x;            // 128 = 2 batches x 64 row-blocks
  int b = bx >> 6, rb = bx & 63;
  int row0 = rb * 16;
  __shared__ float red[256][3];
  __shared__ float lx[16][3];
  __shared__ float st[16][2][CC];
  int t = threadIdx.x;
  int rloc = t >> 4, sl = t & 15;
  const float* Lrow = L + ((size_t)b*NN + row0 + rloc) * NN;
  const float* ipb  = inp + (size_t)b*NN*3;
  float a0=0.f,a1=0.f,a2=0.f;
  for (int m = sl; m < NN; m += 16) {
    float lv = Lrow[m];
    a0 = fmaf(lv, ipb[m*3+0], a0);
    a1 = fmaf(lv, ipb[m*3+1], a1);
    a2 = fmaf(lv, ipb[m*3+2], a2);
  }
  red[t][0]=a0; red[t][1]=a1; red[t][2]=a2;
  __syncthreads();
  if (t < 48) {
    int row = t/3, ci = t%3;
    float s=0.f;
    for (int s2=0; s2<16; ++s2) s += red[row*16+s2][ci];
    lx[row][ci]=s;
  }
  __syncthreads();
  for (int o = t; o < 16*CC; o += 256) {
    int row = o/CC, c = o%CC;
    const float* ir = inp + ((size_t)b*NN + row0 + row)*3;
    float val = bias[c];
    #pragma unroll
    for (int ci=0; ci<3; ++ci)
      val += ir[ci]*W0[ci*CC+c] + lx[row][ci]*W1[ci*CC+c];
    v[((size_t)b*NN + row0 + row)*CC + c] = val;
    st[row][0][c] = val;
    st[row][1][c] = val*val;
  }
  __syncthreads();
  if (t < CC) {
    float s=0.f,q=0.f;
    for (int row=0; row<16; ++row){ s+=st[row][0][t]; q+=st[row][1][t]; }
    vstat[(bx*2+0)*CC + t] = s;
    vstat[(bx*2+1)*CC + t] = q;
  }
}

// ---------------- f32 -> bf16 (RNE) bulk convert: 8 elems/thread/iter ----------------
__global__ __launch_bounds__(256) void k_cvt(
    const float* __restrict__ src, unsigned int* __restrict__ dst, size_t n8)
{
  size_t i = (size_t)blockIdx.x*256 + threadIdx.x;
  size_t stride = (size_t)gridDim.x*256;
  for (; i < n8; i += stride) {
    const uint4* s = (const uint4*)src + i*2;
    uint4 u0 = s[0], u1 = s[1];
    uint4 o;
    #define CV(a,b) ((((a) + 0x7FFFu + (((a)>>16)&1u)) >> 16) | ((((b) + 0x7FFFu + (((b)>>16)&1u)) >> 16) << 16))
    o.x = CV(u0.x,u0.y); o.y = CV(u0.z,u0.w);
    o.z = CV(u1.x,u1.y); o.w = CV(u1.z,u1.w);
    #undef CV
    ((uint4*)dst)[i] = o;
  }
}

// ---------------- A-fragment: 4 consecutive elems, bf16 or f32 ----------------
__device__ __forceinline__ float4 bf4_to_f4(uint2 r) {
  float4 f;
  ((unsigned&)f.x) = r.x << 16;
  ((unsigned&)f.y) = r.x & 0xFFFF0000u;
  ((unsigned&)f.z) = r.y << 16;
  ((unsigned&)f.w) = r.y & 0xFFFF0000u;
  return f;
}
template<typename AT> struct AFr;
template<> struct AFr<unsigned short> {
  uint2 v;
  __device__ __forceinline__ void load(const unsigned short* p){ v = *(const uint2*)p; }
  __device__ __forceinline__ float4 get() const { return bf4_to_f4(v); }
};
template<> struct AFr<float> {
  float4 v;
  __device__ __forceinline__ void load(const float* p){ v = *(const float4*)p; }
  __device__ __forceinline__ float4 get() const { return v; }
};

// ---------------- Dirac: y[m,q] = sum_k A[m,k] * x[k,q] (q=0..19), + y-stats partials ----
// Pipelined streamer: chunk=256 k, double-buffered transposed x in LDS
// (conflict-free ds_read_b128), A prefetched one chunk ahead (reg rotate via
// convert-then-reload). DR=4 rows/wave; demand ~145 VGPR; launch_bounds(256,3)
// caps at 170 -> no scratch spill (round-4 lesson: spill iff demand > cap).
template<int DR, typename AT>
__global__ __launch_bounds__(256,3) void k_dirac(
    const AT* __restrict__ A, const float* __restrict__ x,
    float* __restrict__ y, float* __restrict__ stat, int M, int K)
{
  int b = blockIdx.y;
  A += (size_t)b*M*K; x += (size_t)b*(size_t)K*20; y += (size_t)b*(size_t)M*20;
  __shared__ float xs[2][20][256];
  __shared__ float stS[4][4][20];
  __shared__ float stQ[4][4][20];
  int t = threadIdx.x, lane = t & 63, w = t >> 6;
  int row0 = blockIdx.x*(4*DR) + w*DR;
  float acc[DR][20];
  #pragma unroll
  for (int r=0;r<DR;++r)
    #pragma unroll
    for (int q=0;q<20;++q) acc[r][q]=0.f;

  const float4* xv = (const float4*)x;   // x row k = 5 float4s at k*5
  int nchunk = K >> 8;
  const AT* Abase = A + (size_t)row0*K + (lane<<2);

  { // stage chunk 0 (transposed)
    float4 s0[5];
    #pragma unroll
    for (int i=0;i<5;++i) s0[i] = xv[(size_t)t*5 + i];
    #pragma unroll
    for (int i=0;i<5;++i) {
      xs[0][4*i+0][t]=s0[i].x; xs[0][4*i+1][t]=s0[i].y;
      xs[0][4*i+2][t]=s0[i].z; xs[0][4*i+3][t]=s0[i].w;
    }
  }
  AFr<AT> a[DR];
  #pragma unroll
  for (int r=0;r<DR;++r) a[r].load(Abase + (size_t)r*K);
  __syncthreads();

  for (int c=0; c<nchunk; ++c) {
    int cur = c & 1;
    bool more = (c+1 < nchunk);
    float4 st[5];
    if (more) {                           // issue next x-stage loads early
      size_t kb = (size_t)(c+1)*256 + t;
      #pragma unroll
      for (int i=0;i<5;++i) st[i] = xv[kb*5 + i];
    }
    float4 af[DR];                        // convert current A, then reload a
    #pragma unroll
    for (int r=0;r<DR;++r) af[r] = a[r].get();
    if (more) {
      const AT* An = Abase + (size_t)(c+1)*256;
      #pragma unroll
      for (int r=0;r<DR;++r) a[r].load(An + (size_t)r*K);
    }
    #pragma unroll
    for (int q=0;q<20;++q) {
      float4 xq = *(const float4*)(&xs[cur][q][lane<<2]);
      #pragma unroll
      for (int r=0;r<DR;++r) {
        acc[r][q] = fmaf(af[r].x, xq.x, acc[r][q]);
        acc[r][q] = fmaf(af[r].y, xq.y, acc[r][q]);
        acc[r][q] = fmaf(af[r].z, xq.z, acc[r][q]);
        acc[r][q] = fmaf(af[r].w, xq.w, acc[r][q]);
      }
    }
    if (more) {                           // publish next buffer
      #pragma unroll
      for (int i=0;i<5;++i) {
        xs[cur^1][4*i+0][t]=st[i].x; xs[cur^1][4*i+1][t]=st[i].y;
        xs[cur^1][4*i+2][t]=st[i].z; xs[cur^1][4*i+3][t]=st[i].w;
      }
    }
    __syncthreads();
  }

  #pragma unroll
  for (int r=0;r<DR;++r) {
    #pragma unroll
    for (int q=0;q<20;++q) {
      float s = acc[r][q];
      s += __shfl_xor(s, 1);
      s += __shfl_xor(s, 2);
      s += __shfl_xor(s, 4);
      s += __shfl_xor(s, 8);
      s += __shfl_xor(s, 16);
      s += __shfl_xor(s, 32);
      acc[r][q]=s;                        // all lanes now hold the full sum
    }
    if (lane==0) {
      float4* yp = (float4*)(y + (size_t)(row0+r)*20);
      yp[0] = make_float4(acc[r][0],acc[r][1],acc[r][2],acc[r][3]);
      yp[1] = make_float4(acc[r][4],acc[r][5],acc[r][6],acc[r][7]);
      yp[2] = make_float4(acc[r][8],acc[r][9],acc[r][10],acc[r][11]);
      yp[3] = make_float4(acc[r][12],acc[r][13],acc[r][14],acc[r][15]);
      yp[4] = make_float4(acc[r][16],acc[r][17],acc[r][18],acc[r][19]);
    }
  }
  // per-wave phase stats: channel c = (row&3)*20+q; row0 % 4 == 0 so phase(r)=r&3
  if (lane < 60) {
    int p = lane/20, q = lane%20;
    float s=0.f, sq=0.f;
    #pragma unroll
    for (int r=p; r<DR; r+=4){ float v0=acc[r][q]; s+=v0; sq=fmaf(v0,v0,sq); }
    stS[w][p][q]=s; stQ[w][p][q]=sq;
  }
  if (lane < 20) {
    float s=0.f, sq=0.f;
    #pragma unroll
    for (int r=3; r<DR; r+=4){ float v0=acc[r][lane]; s+=v0; sq=fmaf(v0,v0,sq); }
    stS[w][3][lane]=s; stQ[w][3][lane]=sq;
  }
  __syncthreads();
  int slot = blockIdx.y*gridDim.x + blockIdx.x;
  if (t < 80) {
    int p=t/20, q=t%20;
    stat[((size_t)slot*2+0)*CC + t] = stS[0][p][q]+stS[1][p][q]+stS[2][p][q]+stS[3][p][q];
  } else if (t < 160) {
    int c2=t-80; int p=c2/20, q=c2%20;
    stat[((size_t)slot*2+1)*CC + c2] = stQ[0][p][q]+stQ[1][p][q]+stQ[2][p][q]+stQ[3][p][q];
  }
}

// ---------------- fused BN(fold)+FC+ELU+residual, + output-stats partials (grid slots) ----
__global__ __launch_bounds__(256) void k_fc(
    const float* __restrict__ p1, const float* __restrict__ p2,
    const float* __restrict__ sp1, int ns1,
    const float* __restrict__ sp2, int ns2,
    const float* __restrict__ g, const float* __restrict__ bb,
    const float* __restrict__ W, const float* __restrict__ cb,
    const float* add, float* out,
    float* __restrict__ statout, int rows, float invrows)
{
  __shared__ float Wl[C2*CC];
  __shared__ float ad[2][C2];
  __shared__ float bpl[CC];
  __shared__ float xsh[3][C2];
  __shared__ float st[3][2][CC];
  int t = threadIdx.x;
  if (t < C2) {
    int c = (t<CC)? t : t-CC;
    const float* sp = (t<CC)? sp1 : sp2;
    int ns = (t<CC)? ns1 : ns2;
    float s=0.f,q=0.f;
    for (int i=0;i<ns;++i){ s += sp[(i*2+0)*CC+c]; q += sp[(i*2+1)*CC+c]; }
    float mean = s*invrows;
    float var  = fmaf(-mean, mean, q*invrows);
    float aa   = g[t]*rsqrtf(var + 1e-5f);
    ad[0][t]=aa; ad[1][t]= bb[t] - mean*aa;
  }
  __syncthreads();
  for (int i=t;i<C2*CC;i+=256) Wl[i] = W[i]*ad[0][i/CC];
  if (t < CC) {
    float s = cb[t];
    for (int c2=0;c2<C2;++c2) s = fmaf(ad[1][c2], W[c2*CC+t], s);
    bpl[t]=s;
  }
  __syncthreads();
  int c = t%CC, rs = t/CC;
  bool act = t < 240;
  float ssum=0.f, ssq=0.f;
  for (int r0 = blockIdx.x*3; r0 < rows; r0 += gridDim.x*3) {
    int row = r0 + rs;
    bool ok = act && row < rows;
    if (ok) {
      xsh[rs][c]    = p1[(size_t)row*CC+c];
      xsh[rs][CC+c] = p2[(size_t)row*CC+c];
    }
    __syncthreads();
    if (ok) {
      float acc = bpl[c];
      #pragma unroll 8
      for (int c2=0;c2<C2;++c2) acc = fmaf(xsh[rs][c2], Wl[c2*CC+c], acc);
      acc = acc>0.f ? acc : expm1f(acc);
      acc += add[(size_t)row*CC+c];
      out[(size_t)row*CC+c] = acc;
      ssum += acc; ssq = fmaf(acc,acc,ssq);
    }
    __syncthreads();
  }
  if (act){ st[rs][0][c]=ssum; st[rs][1][c]=ssq; }
  __syncthreads();
  if (t<CC){
    statout[(blockIdx.x*2+0)*CC+t] = st[0][0][t]+st[1][0][t]+st[2][0][t];
    statout[(blockIdx.x*2+1)*CC+t] = st[0][1][t]+st[1][1][t]+st[2][1][t];
  }
}

// ---------------- final: vf = elu(bn1(v2)+bn2(v1)+bn3(v0)) ----------------
__global__ __launch_bounds__(256) void k_final(
    const float* __restrict__ v2, const float* __restrict__ v1, const float* __restrict__ v0,
    const float* __restrict__ s2, const float* __restrict__ s1, const float* __restrict__ s0,
    const float* __restrict__ g1, const float* __restrict__ b1,
    const float* __restrict__ g2, const float* __restrict__ b2,
    const float* __restrict__ g3, const float* __restrict__ b3,
    float* __restrict__ vf)
{
  __shared__ float A[3][CC], D[3][CC];
  int t = threadIdx.x;
  if (t < 240) {
    int set = t/CC, c = t%CC;
    const float* sp  = set==0? s2 : (set==1? s1 : s0);
    const float* gg  = set==0? g1 : (set==1? g2 : g3);
    const float* bbp = set==0? b1 : (set==1? b2 : b3);
    float s=0.f,q=0.f;
    for (int i=0;i<256;++i){ s+=sp[(i*2+0)*CC+c]; q+=sp[(i*2+1)*CC+c]; }
    float mean = s*(1.f/ROWS_Y);
    float var  = fmaf(-mean,mean,q*(1.f/ROWS_Y));
    float aa   = gg[c]*rsqrtf(var+1e-5f);
    A[set][c]=aa; D[set][c]=bbp[c]-mean*aa;
  }
  __syncthreads();
  for (size_t idx = (size_t)blockIdx.x*256 + t; idx < (size_t)ROWS_Y*CC; idx += (size_t)gridDim.x*256) {
    int c = (int)(idx % CC);
    float val = fmaf(v2[idx],A[0][c],D[0][c]) + fmaf(v1[idx],A[1][c],D[1][c]) + fmaf(v0[idx],A[2][c],D[2][c]);
    vf[idx] = val>0.f? val : expm1f(val);
  }
}

// ---------------- w[b,n] = sum_k mask[b,k] L[b,k,n] ----------------
__global__ __launch_bounds__(256) void k_w(
    const float* __restrict__ mask, const float* __restrict__ L, float* __restrict__ w)
{
  int bx = blockIdx.x;            // 32
  int b = bx >> 4, n0 = (bx & 15) * 64;
  int t = threadIdx.x;
  int ks = t >> 6;
  __shared__ float red[4][64];
  float acc=0.f;
  const float* Lb = L + (size_t)b*NN*NN;
  const float* mb = mask + b*NN;
  int n = n0 + (t & 63);
  for (int k = ks*256; k < ks*256+256; ++k)
    acc = fmaf(mb[k], Lb[(size_t)k*NN + n], acc);
  red[ks][t&63]=acc;
  __syncthreads();
  if (t < 64) w[b*NN + n0 + t] = red[0][t]+red[1][t]+red[2][t]+red[3][t];
}

// ---------------- pooled partials: p1 = sum mask*vf, p2 = sum w*vf ----------------
__global__ __launch_bounds__(256) void k_pool(
    const float* __restrict__ vf, const float* __restrict__ mask,
    const float* __restrict__ w, float* __restrict__ part)
{
  int bx = blockIdx.x;            // 16
  int b = bx >> 3, slab = bx & 7;
  int t = threadIdx.x, c = t%CC, rs = t/CC;
  __shared__ float st[3][2][CC];
  if (t<240) {
    float a1=0.f,a2=0.f;
    for (int r = rs; r < 128; r += 3) {
      int row = slab*128 + r;
      float val = vf[((size_t)b*NN + row)*CC + c];
      a1 = fmaf(mask[b*NN+row], val, a1);
      a2 = fmaf(w[b*NN+row],    val, a2);
    }
    st[rs][0][c]=a1; st[rs][1][c]=a2;
  }
  __syncthreads();
  if (t<CC) {
    part[((b*8+slab)*2+0)*CC+t] = st[0][0][t]+st[1][0][t]+st[2][0][t];
    part[((b*8+slab)*2+1)*CC+t] = st[0][1][t]+st[1][1][t]+st[2][1][t];
  }
}

// ---------------- out[b,co] = (p1@W0 + p2@W1)/msum + b2 ----------------
__global__ __launch_bounds__(256) void k_out(
    const float* __restrict__ part, const float* __restrict__ mask,
    const float* __restrict__ W0, const float* __restrict__ W1,
    const float* __restrict__ b2, float* __restrict__ outp)
{
  __shared__ float pl[2][2][CC];
  __shared__ float ms[2];
  int t = threadIdx.x;
  if (t < 160) {
    int b = t/CC, c = t%CC;
    float s1=0.f,s2=0.f;
    for (int slab=0; slab<8; ++slab){
      s1 += part[((b*8+slab)*2+0)*CC+c];
      s2 += part[((b*8+slab)*2+1)*CC+c];
    }
    pl[b][0][c]=s1; pl[b][1][c]=s2;
  }
  if (t>=160 && t<162) {
    int b=t-160; float s=0.f;
    for (int k=0;k<NN;++k) s += mask[b*NN+k];
    ms[b]=s;
  }
  __syncthreads();
  int b = t >> 7, co = t & 127;
  float acc = 0.f;
  #pragma unroll 8
  for (int c=0;c<CC;++c)
    acc += pl[b][0][c]*W0[c*128+co] + pl[b][1][c]*W1[c*128+co];
  outp[t] = acc/ms[b] + b2[co];
}

extern "C" void kernel_launch(void* const* d_in, const int* in_sizes, int n_in,
                              void* d_out, int out_size, void* d_ws, size_t ws_size,
                              hipStream_t stream)
{
  const float* inp  = (const float*)d_in[0];
  const float* L    = (const float*)d_in[1];
  const float* Di   = (const float*)d_in[2];
  const float* DiA  = (const float*)d_in[3];
  const float* mask = (const float*)d_in[4];
  const float* c1W0 = (const float*)d_in[5];
  const float* c1W1 = (const float*)d_in[6];
  const float* c1b  = (const float*)d_in[7];
  const float* bn0g = (const float*)d_in[8];
  const float* bn0b = (const float*)d_in[9];
  const float* fc0W = (const float*)d_in[10];
  const float* fc0b = (const float*)d_in[11];
  const float* bn1g = (const float*)d_in[12];
  const float* bn1b = (const float*)d_in[13];
  const float* fc1W = (const float*)d_in[14];
  const float* fc1b = (const float*)d_in[15];
  const float* fbn1g= (const float*)d_in[16];
  const float* fbn1b= (const float*)d_in[17];
  const float* fbn2g= (const float*)d_in[18];
  const float* fbn2b= (const float*)d_in[19];
  const float* fbn3g= (const float*)d_in[20];
  const float* fbn3b= (const float*)d_in[21];
  const float* c2W0 = (const float*)d_in[22];
  const float* c2W1 = (const float*)d_in[23];
  const float* c2b  = (const float*)d_in[24];

  float* ws = (float*)d_ws;
  size_t off = 0;
  auto alloc = [&](size_t n)->float* { float* p = ws + off; off += (n + 63) & ~(size_t)63; return p; };
  const size_t STFL = (size_t)1024*2*CC;   // stat buffers: up to 1024 slots
  float* vb[3];   for (int i=0;i<3;++i) vb[i]   = alloc((size_t)BB*NN*CC);
  float* fb[2];   for (int i=0;i<2;++i) fb[i]   = alloc((size_t)BB*FF*CC);
  float* Dv       = alloc((size_t)BB*FF*CC);
  float* Df       = alloc((size_t)BB*NN*CC);
  float* vstat[3];for (int i=0;i<3;++i) vstat[i]= alloc(STFL);
  float* fstat[2];for (int i=0;i<2;++i) fstat[i]= alloc(STFL);
  float* dvstat   = alloc(STFL);
  float* dfstat   = alloc(STFL);
  float* vf       = alloc((size_t)BB*NN*CC);
  float* wv       = alloc((size_t)BB*NN);
  float* part     = alloc((size_t)16*2*CC);
  const size_t nDi = (size_t)BB*(4*FF)*(4*NN);      // 67,108,864 elems each
  unsigned short* Dib  = (unsigned short*)alloc(nDi/2);
  unsigned short* DiAb = (unsigned short*)alloc(nDi/2);
  bool usebf = (off*sizeof(float) <= ws_size);

  hipMemsetAsync(fb[0],    0, (size_t)BB*FF*CC*4, stream);
  hipMemsetAsync(fb[1],    0, (size_t)BB*FF*CC*4, stream);
  hipMemsetAsync(vb[1],    0, (size_t)BB*NN*CC*4, stream);
  hipMemsetAsync(fstat[0], 0, (size_t)256*2*CC*4, stream);

  if (usebf) {
    k_cvt<<<4096,256,0,stream>>>(Di,  (unsigned int*)Dib,  nDi/8);
    k_cvt<<<4096,256,0,stream>>>(DiA, (unsigned int*)DiAb, nDi/8);
  }

  k_conv1<<<128,256,0,stream>>>(inp, L, c1W0, c1W1, c1b, vb[0], vstat[0]);

  int cur=0, p1=1, p2=2, fcur=0, fs=0;
  for (int it=0; it<NB_; ++it) {
    if (usebf) k_dirac<4,unsigned short><<<dim3(512,2),256,0,stream>>>(Dib, vb[cur], Dv, dvstat, 4*FF, 4*NN);
    else       k_dirac<4,float         ><<<dim3(512,2),256,0,stream>>>(Di,  vb[cur], Dv, dvstat, 4*FF, 4*NN);
    k_fc<<<256,256,0,stream>>>(fb[fcur], Dv, fstat[fs],256, dvstat,1024,
        bn0g+(size_t)it*C2, bn0b+(size_t)it*C2, fc0W+(size_t)it*C2*CC, fc0b+(size_t)it*CC,
        fb[1-fcur], fb[1-fcur], fstat[1-fs], ROWS_X, 1.f/ROWS_X);
    fcur = 1-fcur; fs = 1-fs;
    if (usebf) k_dirac<4,unsigned short><<<dim3(256,2),256,0,stream>>>(DiAb, fb[fcur], Df, dfstat, 4*NN, 4*FF);
    else       k_dirac<4,float         ><<<dim3(256,2),256,0,stream>>>(DiA,  fb[fcur], Df, dfstat, 4*NN, 4*FF);
    k_fc<<<256,256,0,stream>>>(vb[cur], Df, vstat[cur],(it==0?128:256), dfstat,512,
        bn1g+(size_t)it*C2, bn1b+(size_t)it*C2, fc1W+(size_t)it*C2*CC, fc1b+(size_t)it*CC,
        vb[p1], vb[p2], vstat[p2], ROWS_Y, 1.f/ROWS_Y);
    int tmp=p2; p2=p1; p1=cur; cur=tmp;
  }

  k_final<<<128,256,0,stream>>>(vb[cur],vb[p1],vb[p2], vstat[cur],vstat[p1],vstat[p2],
      fbn1g,fbn1b,fbn2g,fbn2b,fbn3g,fbn3b, vf);
  k_w<<<32,256,0,stream>>>(mask, L, wv);
  k_pool<<<16,256,0,stream>>>(vf, mask, wv, part);
  k_out<<<1,256,0,stream>>>(part, mask, c2W0, c2W1, c2b, (float*)d_out);
}

// Round 6
// 15837.289 us; speedup vs baseline: 1.0585x; 1.0585x over previous
//
#include <hip/hip_runtime.h>
#include <cstdint>

#define BB 2
#define NN 1024
#define FF 2048
#define CC 80
#define C2 160
#define NB_ 15
#define ROWS_X (BB*FF)   /* 4096 */
#define ROWS_Y (BB*NN)   /* 2048 */

// ---------------- conv1: v = in@W0 + (L@in)@W1 + b, + v-stats partials (128 slots) ----------------
__global__ __launch_bounds__(256) void k_conv1(
    const float* __restrict__ inp, const float* __restrict__ L,
    const float* __restrict__ W0, const float* __restrict__ W1,
    const float* __restrict__ bias, float* __restrict__ v,
    float* __restrict__ vstat)
{
  int bx = blockIdx.x;            // 128 = 2 batches x 64 row-blocks
  int b = bx >> 6, rb = bx & 63;
  int row0 = rb * 16;
  __shared__ float red[256][3];
  __shared__ float lx[16][3];
  __shared__ float st[16][2][CC];
  int t = threadIdx.x;
  int rloc = t >> 4, sl = t & 15;
  const float* Lrow = L + ((size_t)b*NN + row0 + rloc) * NN;
  const float* ipb  = inp + (size_t)b*NN*3;
  float a0=0.f,a1=0.f,a2=0.f;
  for (int m = sl; m < NN; m += 16) {
    float lv = Lrow[m];
    a0 = fmaf(lv, ipb[m*3+0], a0);
    a1 = fmaf(lv, ipb[m*3+1], a1);
    a2 = fmaf(lv, ipb[m*3+2], a2);
  }
  red[t][0]=a0; red[t][1]=a1; red[t][2]=a2;
  __syncthreads();
  if (t < 48) {
    int row = t/3, ci = t%3;
    float s=0.f;
    for (int s2=0; s2<16; ++s2) s += red[row*16+s2][ci];
    lx[row][ci]=s;
  }
  __syncthreads();
  for (int o = t; o < 16*CC; o += 256) {
    int row = o/CC, c = o%CC;
    const float* ir = inp + ((size_t)b*NN + row0 + row)*3;
    float val = bias[c];
    #pragma unroll
    for (int ci=0; ci<3; ++ci)
      val += ir[ci]*W0[ci*CC+c] + lx[row][ci]*W1[ci*CC+c];
    v[((size_t)b*NN + row0 + row)*CC + c] = val;
    st[row][0][c] = val;
    st[row][1][c] = val*val;
  }
  __syncthreads();
  if (t < CC) {
    float s=0.f,q=0.f;
    for (int row=0; row<16; ++row){ s+=st[row][0][t]; q+=st[row][1][t]; }
    vstat[(bx*2+0)*CC + t] = s;
    vstat[(bx*2+1)*CC + t] = q;
  }
}

// ---------------- f32 -> bf16 (RNE) bulk convert: 8 elems/thread/iter ----------------
__global__ __launch_bounds__(256) void k_cvt(
    const float* __restrict__ src, unsigned int* __restrict__ dst, size_t n8)
{
  size_t i = (size_t)blockIdx.x*256 + threadIdx.x;
  size_t stride = (size_t)gridDim.x*256;
  for (; i < n8; i += stride) {
    const uint4* s = (const uint4*)src + i*2;
    uint4 u0 = s[0], u1 = s[1];
    uint4 o;
    #define CV(a,b) ((((a) + 0x7FFFu + (((a)>>16)&1u)) >> 16) | ((((b) + 0x7FFFu + (((b)>>16)&1u)) >> 16) << 16))
    o.x = CV(u0.x,u0.y); o.y = CV(u0.z,u0.w);
    o.z = CV(u1.x,u1.y); o.w = CV(u1.z,u1.w);
    #undef CV
    ((uint4*)dst)[i] = o;
  }
}

// ---------------- A-fragment: 4 consecutive elems, bf16 or f32 ----------------
__device__ __forceinline__ float4 bf4_to_f4(uint2 r) {
  float4 f;
  ((unsigned&)f.x) = r.x << 16;
  ((unsigned&)f.y) = r.x & 0xFFFF0000u;
  ((unsigned&)f.z) = r.y << 16;
  ((unsigned&)f.w) = r.y & 0xFFFF0000u;
  return f;
}
template<typename AT> struct AFr;
template<> struct AFr<unsigned short> {
  uint2 v;
  __device__ __forceinline__ void load(const unsigned short* p){ v = *(const uint2*)p; }
  __device__ __forceinline__ float4 get() const { return bf4_to_f4(v); }
};
template<> struct AFr<float> {
  float4 v;
  __device__ __forceinline__ void load(const float* p){ v = *(const float4*)p; }
  __device__ __forceinline__ float4 get() const { return v; }
};

// ---------------- Dirac: y[m,q] = sum_k A[m,k] * x[k,q] (q=0..19), + y-stats partials ----
// Pipelined streamer: chunk=256 k, double-buffered transposed x in LDS
// (conflict-free ds_read_b128), A prefetched one chunk ahead. DR=4 rows/wave.
// amdgpu_waves_per_eu(2,2): PIN the allocator range (min=max=2 waves/EU ->
// 256-VGPR budget). Rounds 2/4/5 showed LLVM's min-only hint chases occupancy
// (84..128 VGPR vs ~145 demand) and spills ~1.5GB/dispatch through scratch.
template<int DR, typename AT>
__global__ __launch_bounds__(256) __attribute__((amdgpu_waves_per_eu(2,2)))
void k_dirac(
    const AT* __restrict__ A, const float* __restrict__ x,
    float* __restrict__ y, float* __restrict__ stat, int M, int K)
{
  int b = blockIdx.y;
  A += (size_t)b*M*K; x += (size_t)b*(size_t)K*20; y += (size_t)b*(size_t)M*20;
  __shared__ float xs[2][20][256];
  __shared__ float stS[4][4][20];
  __shared__ float stQ[4][4][20];
  int t = threadIdx.x, lane = t & 63, w = t >> 6;
  int row0 = blockIdx.x*(4*DR) + w*DR;
  float acc[DR][20];
  #pragma unroll
  for (int r=0;r<DR;++r)
    #pragma unroll
    for (int q=0;q<20;++q) acc[r][q]=0.f;

  const float4* xv = (const float4*)x;   // x row k = 5 float4s at k*5
  int nchunk = K >> 8;
  const AT* Abase = A + (size_t)row0*K + (lane<<2);

  { // stage chunk 0 (transposed)
    float4 s0[5];
    #pragma unroll
    for (int i=0;i<5;++i) s0[i] = xv[(size_t)t*5 + i];
    #pragma unroll
    for (int i=0;i<5;++i) {
      xs[0][4*i+0][t]=s0[i].x; xs[0][4*i+1][t]=s0[i].y;
      xs[0][4*i+2][t]=s0[i].z; xs[0][4*i+3][t]=s0[i].w;
    }
  }
  AFr<AT> a[DR];
  #pragma unroll
  for (int r=0;r<DR;++r) a[r].load(Abase + (size_t)r*K);
  __syncthreads();

  for (int c=0; c<nchunk; ++c) {
    int cur = c & 1;
    bool more = (c+1 < nchunk);
    float4 st[5];
    if (more) {                           // issue next x-stage loads early
      size_t kb = (size_t)(c+1)*256 + t;
      #pragma unroll
      for (int i=0;i<5;++i) st[i] = xv[kb*5 + i];
    }
    float4 af[DR];                        // convert current A, then reload a
    #pragma unroll
    for (int r=0;r<DR;++r) af[r] = a[r].get();
    if (more) {
      const AT* An = Abase + (size_t)(c+1)*256;
      #pragma unroll
      for (int r=0;r<DR;++r) a[r].load(An + (size_t)r*K);
    }
    #pragma unroll
    for (int q=0;q<20;++q) {
      float4 xq = *(const float4*)(&xs[cur][q][lane<<2]);
      #pragma unroll
      for (int r=0;r<DR;++r) {
        acc[r][q] = fmaf(af[r].x, xq.x, acc[r][q]);
        acc[r][q] = fmaf(af[r].y, xq.y, acc[r][q]);
        acc[r][q] = fmaf(af[r].z, xq.z, acc[r][q]);
        acc[r][q] = fmaf(af[r].w, xq.w, acc[r][q]);
      }
    }
    if (more) {                           // publish next buffer
      #pragma unroll
      for (int i=0;i<5;++i) {
        xs[cur^1][4*i+0][t]=st[i].x; xs[cur^1][4*i+1][t]=st[i].y;
        xs[cur^1][4*i+2][t]=st[i].z; xs[cur^1][4*i+3][t]=st[i].w;
      }
    }
    __syncthreads();
  }

  #pragma unroll
  for (int r=0;r<DR;++r) {
    #pragma unroll
    for (int q=0;q<20;++q) {
      float s = acc[r][q];
      s += __shfl_xor(s, 1);
      s += __shfl_xor(s, 2);
      s += __shfl_xor(s, 4);
      s += __shfl_xor(s, 8);
      s += __shfl_xor(s, 16);
      s += __shfl_xor(s, 32);
      acc[r][q]=s;                        // all lanes now hold the full sum
    }
    if (lane==0) {
      float4* yp = (float4*)(y + (size_t)(row0+r)*20);
      yp[0] = make_float4(acc[r][0],acc[r][1],acc[r][2],acc[r][3]);
      yp[1] = make_float4(acc[r][4],acc[r][5],acc[r][6],acc[r][7]);
      yp[2] = make_float4(acc[r][8],acc[r][9],acc[r][10],acc[r][11]);
      yp[3] = make_float4(acc[r][12],acc[r][13],acc[r][14],acc[r][15]);
      yp[4] = make_float4(acc[r][16],acc[r][17],acc[r][18],acc[r][19]);
    }
  }
  // per-wave phase stats: channel c = (row&3)*20+q; row0 % 4 == 0 so phase(r)=r&3
  if (lane < 60) {
    int p = lane/20, q = lane%20;
    float s=0.f, sq=0.f;
    #pragma unroll
    for (int r=p; r<DR; r+=4){ float v0=acc[r][q]; s+=v0; sq=fmaf(v0,v0,sq); }
    stS[w][p][q]=s; stQ[w][p][q]=sq;
  }
  if (lane < 20) {
    float s=0.f, sq=0.f;
    #pragma unroll
    for (int r=3; r<DR; r+=4){ float v0=acc[r][lane]; s+=v0; sq=fmaf(v0,v0,sq); }
    stS[w][3][lane]=s; stQ[w][3][lane]=sq;
  }
  __syncthreads();
  int slot = blockIdx.y*gridDim.x + blockIdx.x;
  if (t < 80) {
    int p=t/20, q=t%20;
    stat[((size_t)slot*2+0)*CC + t] = stS[0][p][q]+stS[1][p][q]+stS[2][p][q]+stS[3][p][q];
  } else if (t < 160) {
    int c2=t-80; int p=c2/20, q=c2%20;
    stat[((size_t)slot*2+1)*CC + c2] = stQ[0][p][q]+stQ[1][p][q]+stQ[2][p][q]+stQ[3][p][q];
  }
}

// ---------------- fused BN(fold)+FC+ELU+residual, + output-stats partials (grid slots) ----
__global__ __launch_bounds__(256) void k_fc(
    const float* __restrict__ p1, const float* __restrict__ p2,
    const float* __restrict__ sp1, int ns1,
    const float* __restrict__ sp2, int ns2,
    const float* __restrict__ g, const float* __restrict__ bb,
    const float* __restrict__ W, const float* __restrict__ cb,
    const float* add, float* out,
    float* __restrict__ statout, int rows, float invrows)
{
  __shared__ float Wl[C2*CC];
  __shared__ float ad[2][C2];
  __shared__ float bpl[CC];
  __shared__ float xsh[3][C2];
  __shared__ float st[3][2][CC];
  int t = threadIdx.x;
  if (t < C2) {
    int c = (t<CC)? t : t-CC;
    const float* sp = (t<CC)? sp1 : sp2;
    int ns = (t<CC)? ns1 : ns2;
    float s=0.f,q=0.f;
    for (int i=0;i<ns;++i){ s += sp[(i*2+0)*CC+c]; q += sp[(i*2+1)*CC+c]; }
    float mean = s*invrows;
    float var  = fmaf(-mean, mean, q*invrows);
    float aa   = g[t]*rsqrtf(var + 1e-5f);
    ad[0][t]=aa; ad[1][t]= bb[t] - mean*aa;
  }
  __syncthreads();
  for (int i=t;i<C2*CC;i+=256) Wl[i] = W[i]*ad[0][i/CC];
  if (t < CC) {
    float s = cb[t];
    for (int c2=0;c2<C2;++c2) s = fmaf(ad[1][c2], W[c2*CC+t], s);
    bpl[t]=s;
  }
  __syncthreads();
  int c = t%CC, rs = t/CC;
  bool act = t < 240;
  float ssum=0.f, ssq=0.f;
  for (int r0 = blockIdx.x*3; r0 < rows; r0 += gridDim.x*3) {
    int row = r0 + rs;
    bool ok = act && row < rows;
    if (ok) {
      xsh[rs][c]    = p1[(size_t)row*CC+c];
      xsh[rs][CC+c] = p2[(size_t)row*CC+c];
    }
    __syncthreads();
    if (ok) {
      float acc = bpl[c];
      #pragma unroll 8
      for (int c2=0;c2<C2;++c2) acc = fmaf(xsh[rs][c2], Wl[c2*CC+c], acc);
      acc = acc>0.f ? acc : expm1f(acc);
      acc += add[(size_t)row*CC+c];
      out[(size_t)row*CC+c] = acc;
      ssum += acc; ssq = fmaf(acc,acc,ssq);
    }
    __syncthreads();
  }
  if (act){ st[rs][0][c]=ssum; st[rs][1][c]=ssq; }
  __syncthreads();
  if (t<CC){
    statout[(blockIdx.x*2+0)*CC+t] = st[0][0][t]+st[1][0][t]+st[2][0][t];
    statout[(blockIdx.x*2+1)*CC+t] = st[0][1][t]+st[1][1][t]+st[2][1][t];
  }
}

// ---------------- final: vf = elu(bn1(v2)+bn2(v1)+bn3(v0)) ----------------
__global__ __launch_bounds__(256) void k_final(
    const float* __restrict__ v2, const float* __restrict__ v1, const float* __restrict__ v0,
    const float* __restrict__ s2, const float* __restrict__ s1, const float* __restrict__ s0,
    const float* __restrict__ g1, const float* __restrict__ b1,
    const float* __restrict__ g2, const float* __restrict__ b2,
    const float* __restrict__ g3, const float* __restrict__ b3,
    float* __restrict__ vf)
{
  __shared__ float A[3][CC], D[3][CC];
  int t = threadIdx.x;
  if (t < 240) {
    int set = t/CC, c = t%CC;
    const float* sp  = set==0? s2 : (set==1? s1 : s0);
    const float* gg  = set==0? g1 : (set==1? g2 : g3);
    const float* bbp = set==0? b1 : (set==1? b2 : b3);
    float s=0.f,q=0.f;
    for (int i=0;i<256;++i){ s+=sp[(i*2+0)*CC+c]; q+=sp[(i*2+1)*CC+c]; }
    float mean = s*(1.f/ROWS_Y);
    float var  = fmaf(-mean,mean,q*(1.f/ROWS_Y));
    float aa   = gg[c]*rsqrtf(var+1e-5f);
    A[set][c]=aa; D[set][c]=bbp[c]-mean*aa;
  }
  __syncthreads();
  for (size_t idx = (size_t)blockIdx.x*256 + t; idx < (size_t)ROWS_Y*CC; idx += (size_t)gridDim.x*256) {
    int c = (int)(idx % CC);
    float val = fmaf(v2[idx],A[0][c],D[0][c]) + fmaf(v1[idx],A[1][c],D[1][c]) + fmaf(v0[idx],A[2][c],D[2][c]);
    vf[idx] = val>0.f? val : expm1f(val);
  }
}

// ---------------- w[b,n] = sum_k mask[b,k] L[b,k,n] ----------------
__global__ __launch_bounds__(256) void k_w(
    const float* __restrict__ mask, const float* __restrict__ L, float* __restrict__ w)
{
  int bx = blockIdx.x;            // 32
  int b = bx >> 4, n0 = (bx & 15) * 64;
  int t = threadIdx.x;
  int ks = t >> 6;
  __shared__ float red[4][64];
  float acc=0.f;
  const float* Lb = L + (size_t)b*NN*NN;
  const float* mb = mask + b*NN;
  int n = n0 + (t & 63);
  for (int k = ks*256; k < ks*256+256; ++k)
    acc = fmaf(mb[k], Lb[(size_t)k*NN + n], acc);
  red[ks][t&63]=acc;
  __syncthreads();
  if (t < 64) w[b*NN + n0 + t] = red[0][t]+red[1][t]+red[2][t]+red[3][t];
}

// ---------------- pooled partials: p1 = sum mask*vf, p2 = sum w*vf ----------------
__global__ __launch_bounds__(256) void k_pool(
    const float* __restrict__ vf, const float* __restrict__ mask,
    const float* __restrict__ w, float* __restrict__ part)
{
  int bx = blockIdx.x;            // 16
  int b = bx >> 3, slab = bx & 7;
  int t = threadIdx.x, c = t%CC, rs = t/CC;
  __shared__ float st[3][2][CC];
  if (t<240) {
    float a1=0.f,a2=0.f;
    for (int r = rs; r < 128; r += 3) {
      int row = slab*128 + r;
      float val = vf[((size_t)b*NN + row)*CC + c];
      a1 = fmaf(mask[b*NN+row], val, a1);
      a2 = fmaf(w[b*NN+row],    val, a2);
    }
    st[rs][0][c]=a1; st[rs][1][c]=a2;
  }
  __syncthreads();
  if (t<CC) {
    part[((b*8+slab)*2+0)*CC+t] = st[0][0][t]+st[1][0][t]+st[2][0][t];
    part[((b*8+slab)*2+1)*CC+t] = st[0][1][t]+st[1][1][t]+st[2][1][t];
  }
}

// ---------------- out[b,co] = (p1@W0 + p2@W1)/msum + b2 ----------------
__global__ __launch_bounds__(256) void k_out(
    const float* __restrict__ part, const float* __restrict__ mask,
    const float* __restrict__ W0, const float* __restrict__ W1,
    const float* __restrict__ b2, float* __restrict__ outp)
{
  __shared__ float pl[2][2][CC];
  __shared__ float ms[2];
  int t = threadIdx.x;
  if (t < 160) {
    int b = t/CC, c = t%CC;
    float s1=0.f,s2=0.f;
    for (int slab=0; slab<8; ++slab){
      s1 += part[((b*8+slab)*2+0)*CC+c];
      s2 += part[((b*8+slab)*2+1)*CC+c];
    }
    pl[b][0][c]=s1; pl[b][1][c]=s2;
  }
  if (t>=160 && t<162) {
    int b=t-160; float s=0.f;
    for (int k=0;k<NN;++k) s += mask[b*NN+k];
    ms[b]=s;
  }
  __syncthreads();
  int b = t >> 7, co = t & 127;
  float acc = 0.f;
  #pragma unroll 8
  for (int c=0;c<CC;++c)
    acc += pl[b][0][c]*W0[c*128+co] + pl[b][1][c]*W1[c*128+co];
  outp[t] = acc/ms[b] + b2[co];
}

extern "C" void kernel_launch(void* const* d_in, const int* in_sizes, int n_in,
                              void* d_out, int out_size, void* d_ws, size_t ws_size,
                              hipStream_t stream)
{
  const float* inp  = (const float*)d_in[0];
  const float* L    = (const float*)d_in[1];
  const float* Di   = (const float*)d_in[2];
  const float* DiA  = (const float*)d_in[3];
  const float* mask = (const float*)d_in[4];
  const float* c1W0 = (const float*)d_in[5];
  const float* c1W1 = (const float*)d_in[6];
  const float* c1b  = (const float*)d_in[7];
  const float* bn0g = (const float*)d_in[8];
  const float* bn0b = (const float*)d_in[9];
  const float* fc0W = (const float*)d_in[10];
  const float* fc0b = (const float*)d_in[11];
  const float* bn1g = (const float*)d_in[12];
  const float* bn1b = (const float*)d_in[13];
  const float* fc1W = (const float*)d_in[14];
  const float* fc1b = (const float*)d_in[15];
  const float* fbn1g= (const float*)d_in[16];
  const float* fbn1b= (const float*)d_in[17];
  const float* fbn2g= (const float*)d_in[18];
  const float* fbn2b= (const float*)d_in[19];
  const float* fbn3g= (const float*)d_in[20];
  const float* fbn3b= (const float*)d_in[21];
  const float* c2W0 = (const float*)d_in[22];
  const float* c2W1 = (const float*)d_in[23];
  const float* c2b  = (const float*)d_in[24];

  float* ws = (float*)d_ws;
  size_t off = 0;
  auto alloc = [&](size_t n)->float* { float* p = ws + off; off += (n + 63) & ~(size_t)63; return p; };
  const size_t STFL = (size_t)1024*2*CC;   // stat buffers: up to 1024 slots
  float* vb[3];   for (int i=0;i<3;++i) vb[i]   = alloc((size_t)BB*NN*CC);
  float* fb[2];   for (int i=0;i<2;++i) fb[i]   = alloc((size_t)BB*FF*CC);
  float* Dv       = alloc((size_t)BB*FF*CC);
  float* Df       = alloc((size_t)BB*NN*CC);
  float* vstat[3];for (int i=0;i<3;++i) vstat[i]= alloc(STFL);
  float* fstat[2];for (int i=0;i<2;++i) fstat[i]= alloc(STFL);
  float* dvstat   = alloc(STFL);
  float* dfstat   = alloc(STFL);
  float* vf       = alloc((size_t)BB*NN*CC);
  float* wv       = alloc((size_t)BB*NN);
  float* part     = alloc((size_t)16*2*CC);
  const size_t nDi = (size_t)BB*(4*FF)*(4*NN);      // 67,108,864 elems each
  unsigned short* Dib  = (unsigned short*)alloc(nDi/2);
  unsigned short* DiAb = (unsigned short*)alloc(nDi/2);
  bool usebf = (off*sizeof(float) <= ws_size);

  hipMemsetAsync(fb[0],    0, (size_t)BB*FF*CC*4, stream);
  hipMemsetAsync(fb[1],    0, (size_t)BB*FF*CC*4, stream);
  hipMemsetAsync(vb[1],    0, (size_t)BB*NN*CC*4, stream);
  hipMemsetAsync(fstat[0], 0, (size_t)256*2*CC*4, stream);

  if (usebf) {
    k_cvt<<<4096,256,0,stream>>>(Di,  (unsigned int*)Dib,  nDi/8);
    k_cvt<<<4096,256,0,stream>>>(DiA, (unsigned int*)DiAb, nDi/8);
  }

  k_conv1<<<128,256,0,stream>>>(inp, L, c1W0, c1W1, c1b, vb[0], vstat[0]);

  int cur=0, p1=1, p2=2, fcur=0, fs=0;
  for (int it=0; it<NB_; ++it) {
    if (usebf) k_dirac<4,unsigned short><<<dim3(512,2),256,0,stream>>>(Dib, vb[cur], Dv, dvstat, 4*FF, 4*NN);
    else       k_dirac<4,float         ><<<dim3(512,2),256,0,stream>>>(Di,  vb[cur], Dv, dvstat, 4*FF, 4*NN);
    k_fc<<<256,256,0,stream>>>(fb[fcur], Dv, fstat[fs],256, dvstat,1024,
        bn0g+(size_t)it*C2, bn0b+(size_t)it*C2, fc0W+(size_t)it*C2*CC, fc0b+(size_t)it*CC,
        fb[1-fcur], fb[1-fcur], fstat[1-fs], ROWS_X, 1.f/ROWS_X);
    fcur = 1-fcur; fs = 1-fs;
    if (usebf) k_dirac<4,unsigned short><<<dim3(256,2),256,0,stream>>>(DiAb, fb[fcur], Df, dfstat, 4*NN, 4*FF);
    else       k_dirac<4,float         ><<<dim3(256,2),256,0,stream>>>(DiA,  fb[fcur], Df, dfstat, 4*NN, 4*FF);
    k_fc<<<256,256,0,stream>>>(vb[cur], Df, vstat[cur],(it==0?128:256), dfstat,512,
        bn1g+(size_t)it*C2, bn1b+(size_t)it*C2, fc1W+(size_t)it*C2*CC, fc1b+(size_t)it*CC,
        vb[p1], vb[p2], vstat[p2], ROWS_Y, 1.f/ROWS_Y);
    int tmp=p2; p2=p1; p1=cur; cur=tmp;
  }

  k_final<<<128,256,0,stream>>>(vb[cur],vb[p1],vb[p2], vstat[cur],vstat[p1],vstat[p2],
      fbn1g,fbn1b,fbn2g,fbn2b,fbn3g,fbn3b, vf);
  k_w<<<32,256,0,stream>>>(mask, L, wv);
  k_pool<<<16,256,0,stream>>>(vf, mask, wv, part);
  k_out<<<1,256,0,stream>>>(part, mask, c2W0, c2W1, c2b, (float*)d_out);
}

// Round 7
// 8880.375 us; speedup vs baseline: 1.8878x; 1.7834x over previous
//
#include <hip/hip_runtime.h>
#include <cstdint>

#define BB 2
#define NN 1024
#define FF 2048
#define CC 80
#define C2 160
#define NB_ 15
#define ROWS_X (BB*FF)   /* 4096 */
#define ROWS_Y (BB*NN)   /* 2048 */

// ---------------- conv1: v = in@W0 + (L@in)@W1 + b, + v-stats partials (128 slots) ----------------
__global__ __launch_bounds__(256) void k_conv1(
    const float* __restrict__ inp, const float* __restrict__ L,
    const float* __restrict__ W0, const float* __restrict__ W1,
    const float* __restrict__ bias, float* __restrict__ v,
    float* __restrict__ vstat)
{
  int bx = blockIdx.x;            // 128 = 2 batches x 64 row-blocks
  int b = bx >> 6, rb = bx & 63;
  int row0 = rb * 16;
  __shared__ float red[256][3];
  __shared__ float lx[16][3];
  __shared__ float st[16][2][CC];
  int t = threadIdx.x;
  int rloc = t >> 4, sl = t & 15;
  const float* Lrow = L + ((size_t)b*NN + row0 + rloc) * NN;
  const float* ipb  = inp + (size_t)b*NN*3;
  float a0=0.f,a1=0.f,a2=0.f;
  for (int m = sl; m < NN; m += 16) {
    float lv = Lrow[m];
    a0 = fmaf(lv, ipb[m*3+0], a0);
    a1 = fmaf(lv, ipb[m*3+1], a1);
    a2 = fmaf(lv, ipb[m*3+2], a2);
  }
  red[t][0]=a0; red[t][1]=a1; red[t][2]=a2;
  __syncthreads();
  if (t < 48) {
    int row = t/3, ci = t%3;
    float s=0.f;
    for (int s2=0; s2<16; ++s2) s += red[row*16+s2][ci];
    lx[row][ci]=s;
  }
  __syncthreads();
  for (int o = t; o < 16*CC; o += 256) {
    int row = o/CC, c = o%CC;
    const float* ir = inp + ((size_t)b*NN + row0 + row)*3;
    float val = bias[c];
    #pragma unroll
    for (int ci=0; ci<3; ++ci)
      val += ir[ci]*W0[ci*CC+c] + lx[row][ci]*W1[ci*CC+c];
    v[((size_t)b*NN + row0 + row)*CC + c] = val;
    st[row][0][c] = val;
    st[row][1][c] = val*val;
  }
  __syncthreads();
  if (t < CC) {
    float s=0.f,q=0.f;
    for (int row=0; row<16; ++row){ s+=st[row][0][t]; q+=st[row][1][t]; }
    vstat[(bx*2+0)*CC + t] = s;
    vstat[(bx*2+1)*CC + t] = q;
  }
}

// ---------------- f32 -> bf16 (RNE) bulk convert: 8 elems/thread/iter ----------------
__global__ __launch_bounds__(256) void k_cvt(
    const float* __restrict__ src, unsigned int* __restrict__ dst, size_t n8)
{
  size_t i = (size_t)blockIdx.x*256 + threadIdx.x;
  size_t stride = (size_t)gridDim.x*256;
  for (; i < n8; i += stride) {
    const uint4* s = (const uint4*)src + i*2;
    uint4 u0 = s[0], u1 = s[1];
    uint4 o;
    #define CV(a,b) ((((a) + 0x7FFFu + (((a)>>16)&1u)) >> 16) | ((((b) + 0x7FFFu + (((b)>>16)&1u)) >> 16) << 16))
    o.x = CV(u0.x,u0.y); o.y = CV(u0.z,u0.w);
    o.z = CV(u1.x,u1.y); o.w = CV(u1.z,u1.w);
    #undef CV
    ((uint4*)dst)[i] = o;
  }
}

// ---------------- A-fragment: 4 consecutive elems, bf16 or f32 ----------------
__device__ __forceinline__ float4 bf4_to_f4(uint2 r) {
  float4 f;
  ((unsigned&)f.x) = r.x << 16;
  ((unsigned&)f.y) = r.x & 0xFFFF0000u;
  ((unsigned&)f.z) = r.y << 16;
  ((unsigned&)f.w) = r.y & 0xFFFF0000u;
  return f;
}
template<typename AT> struct AFr;
template<> struct AFr<unsigned short> {
  uint2 v;
  __device__ __forceinline__ void load(const unsigned short* p){ v = *(const uint2*)p; }
  __device__ __forceinline__ float4 get() const { return bf4_to_f4(v); }
};
template<> struct AFr<float> {
  float4 v;
  __device__ __forceinline__ void load(const float* p){ v = *(const float4*)p; }
  __device__ __forceinline__ float4 get() const { return v; }
};

// ---------------- Dirac: y[m,q] = sum_k A[m,k] * x[k,q] (q=0..19), + y-stats partials ----
// Pipelined streamer: chunk=256 k, double-buffered transposed x in LDS
// (conflict-free ds_read_b128), A prefetched one chunk ahead. DR=4 rows/wave.
// CRITICAL (rounds 4-6 post-mortem): acc[][] must ONLY ever be indexed with
// compile-time constants. Any runtime index (the old stats tail used
// acc[r][lane%20]) demotes the whole array to scratch -> ~1.4 GB/dispatch of
// scratch traffic and 10x slowdown. Stats now written by lane 0 with fully
// unrolled constant indices.
template<int DR, typename AT>
__global__ __launch_bounds__(256) __attribute__((amdgpu_waves_per_eu(2,2)))
void k_dirac(
    const AT* __restrict__ A, const float* __restrict__ x,
    float* __restrict__ y, float* __restrict__ stat, int M, int K)
{
  static_assert(DR == 4, "stats channel mapping assumes DR==4");
  int b = blockIdx.y;
  A += (size_t)b*M*K; x += (size_t)b*(size_t)K*20; y += (size_t)b*(size_t)M*20;
  __shared__ float xs[2][20][256];
  __shared__ float stS[4][CC];
  __shared__ float stQ[4][CC];
  int t = threadIdx.x, lane = t & 63, w = t >> 6;
  int row0 = blockIdx.x*(4*DR) + w*DR;
  float acc[DR][20];
  #pragma unroll
  for (int r=0;r<DR;++r)
    #pragma unroll
    for (int q=0;q<20;++q) acc[r][q]=0.f;

  const float4* xv = (const float4*)x;   // x row k = 5 float4s at k*5
  int nchunk = K >> 8;
  const AT* Abase = A + (size_t)row0*K + (lane<<2);

  { // stage chunk 0 (transposed)
    float4 s0[5];
    #pragma unroll
    for (int i=0;i<5;++i) s0[i] = xv[(size_t)t*5 + i];
    #pragma unroll
    for (int i=0;i<5;++i) {
      xs[0][4*i+0][t]=s0[i].x; xs[0][4*i+1][t]=s0[i].y;
      xs[0][4*i+2][t]=s0[i].z; xs[0][4*i+3][t]=s0[i].w;
    }
  }
  AFr<AT> a[DR];
  #pragma unroll
  for (int r=0;r<DR;++r) a[r].load(Abase + (size_t)r*K);
  __syncthreads();

  for (int c=0; c<nchunk; ++c) {
    int cur = c & 1;
    bool more = (c+1 < nchunk);
    float4 st[5];
    if (more) {                           // issue next x-stage loads early
      size_t kb = (size_t)(c+1)*256 + t;
      #pragma unroll
      for (int i=0;i<5;++i) st[i] = xv[kb*5 + i];
    }
    float4 af[DR];                        // convert current A, then reload a
    #pragma unroll
    for (int r=0;r<DR;++r) af[r] = a[r].get();
    if (more) {
      const AT* An = Abase + (size_t)(c+1)*256;
      #pragma unroll
      for (int r=0;r<DR;++r) a[r].load(An + (size_t)r*K);
    }
    #pragma unroll
    for (int q=0;q<20;++q) {
      float4 xq = *(const float4*)(&xs[cur][q][lane<<2]);
      #pragma unroll
      for (int r=0;r<DR;++r) {
        acc[r][q] = fmaf(af[r].x, xq.x, acc[r][q]);
        acc[r][q] = fmaf(af[r].y, xq.y, acc[r][q]);
        acc[r][q] = fmaf(af[r].z, xq.z, acc[r][q]);
        acc[r][q] = fmaf(af[r].w, xq.w, acc[r][q]);
      }
    }
    if (more) {                           // publish next buffer
      #pragma unroll
      for (int i=0;i<5;++i) {
        xs[cur^1][4*i+0][t]=st[i].x; xs[cur^1][4*i+1][t]=st[i].y;
        xs[cur^1][4*i+2][t]=st[i].z; xs[cur^1][4*i+3][t]=st[i].w;
      }
    }
    __syncthreads();
  }

  #pragma unroll
  for (int r=0;r<DR;++r) {
    #pragma unroll
    for (int q=0;q<20;++q) {
      float s = acc[r][q];
      s += __shfl_xor(s, 1);
      s += __shfl_xor(s, 2);
      s += __shfl_xor(s, 4);
      s += __shfl_xor(s, 8);
      s += __shfl_xor(s, 16);
      s += __shfl_xor(s, 32);
      acc[r][q]=s;                        // all lanes now hold the full sum
    }
    if (lane==0) {
      float4* yp = (float4*)(y + (size_t)(row0+r)*20);
      yp[0] = make_float4(acc[r][0],acc[r][1],acc[r][2],acc[r][3]);
      yp[1] = make_float4(acc[r][4],acc[r][5],acc[r][6],acc[r][7]);
      yp[2] = make_float4(acc[r][8],acc[r][9],acc[r][10],acc[r][11]);
      yp[3] = make_float4(acc[r][12],acc[r][13],acc[r][14],acc[r][15]);
      yp[4] = make_float4(acc[r][16],acc[r][17],acc[r][18],acc[r][19]);
    }
  }
  // stats: post-butterfly all lanes hold identical sums; lane 0 per wave
  // writes its wave's 80 channels with COMPILE-TIME indices only.
  // Channel mapping: y row m -> reshape [.,80] channel (m%4)*20+q; row0%4==0
  // so phase(r)==r for DR=4.
  if (lane == 0) {
    #pragma unroll
    for (int r=0;r<DR;++r)
      #pragma unroll
      for (int q=0;q<20;++q) {
        float v0 = acc[r][q];
        stS[w][r*20+q] = v0;
        stQ[w][r*20+q] = v0*v0;
      }
  }
  __syncthreads();
  int slot = blockIdx.y*gridDim.x + blockIdx.x;
  if (t < 80) {
    stat[((size_t)slot*2+0)*CC + t] = stS[0][t]+stS[1][t]+stS[2][t]+stS[3][t];
  } else if (t < 160) {
    int c2=t-80;
    stat[((size_t)slot*2+1)*CC + c2] = stQ[0][c2]+stQ[1][c2]+stQ[2][c2]+stQ[3][c2];
  }
}

// ---------------- fused BN(fold)+FC+ELU+residual, + output-stats partials (grid slots) ----
__global__ __launch_bounds__(256) void k_fc(
    const float* __restrict__ p1, const float* __restrict__ p2,
    const float* __restrict__ sp1, int ns1,
    const float* __restrict__ sp2, int ns2,
    const float* __restrict__ g, const float* __restrict__ bb,
    const float* __restrict__ W, const float* __restrict__ cb,
    const float* add, float* out,
    float* __restrict__ statout, int rows, float invrows)
{
  __shared__ float Wl[C2*CC];
  __shared__ float ad[2][C2];
  __shared__ float bpl[CC];
  __shared__ float xsh[3][C2];
  __shared__ float st[3][2][CC];
  int t = threadIdx.x;
  if (t < C2) {
    int c = (t<CC)? t : t-CC;
    const float* sp = (t<CC)? sp1 : sp2;
    int ns = (t<CC)? ns1 : ns2;
    float s=0.f,q=0.f;
    for (int i=0;i<ns;++i){ s += sp[(i*2+0)*CC+c]; q += sp[(i*2+1)*CC+c]; }
    float mean = s*invrows;
    float var  = fmaf(-mean, mean, q*invrows);
    float aa   = g[t]*rsqrtf(var + 1e-5f);
    ad[0][t]=aa; ad[1][t]= bb[t] - mean*aa;
  }
  __syncthreads();
  for (int i=t;i<C2*CC;i+=256) Wl[i] = W[i]*ad[0][i/CC];
  if (t < CC) {
    float s = cb[t];
    for (int c2=0;c2<C2;++c2) s = fmaf(ad[1][c2], W[c2*CC+t], s);
    bpl[t]=s;
  }
  __syncthreads();
  int c = t%CC, rs = t/CC;
  bool act = t < 240;
  float ssum=0.f, ssq=0.f;
  for (int r0 = blockIdx.x*3; r0 < rows; r0 += gridDim.x*3) {
    int row = r0 + rs;
    bool ok = act && row < rows;
    if (ok) {
      xsh[rs][c]    = p1[(size_t)row*CC+c];
      xsh[rs][CC+c] = p2[(size_t)row*CC+c];
    }
    __syncthreads();
    if (ok) {
      float acc = bpl[c];
      #pragma unroll 8
      for (int c2=0;c2<C2;++c2) acc = fmaf(xsh[rs][c2], Wl[c2*CC+c], acc);
      acc = acc>0.f ? acc : expm1f(acc);
      acc += add[(size_t)row*CC+c];
      out[(size_t)row*CC+c] = acc;
      ssum += acc; ssq = fmaf(acc,acc,ssq);
    }
    __syncthreads();
  }
  if (act){ st[rs][0][c]=ssum; st[rs][1][c]=ssq; }
  __syncthreads();
  if (t<CC){
    statout[(blockIdx.x*2+0)*CC+t] = st[0][0][t]+st[1][0][t]+st[2][0][t];
    statout[(blockIdx.x*2+1)*CC+t] = st[0][1][t]+st[1][1][t]+st[2][1][t];
  }
}

// ---------------- final: vf = elu(bn1(v2)+bn2(v1)+bn3(v0)) ----------------
__global__ __launch_bounds__(256) void k_final(
    const float* __restrict__ v2, const float* __restrict__ v1, const float* __restrict__ v0,
    const float* __restrict__ s2, const float* __restrict__ s1, const float* __restrict__ s0,
    const float* __restrict__ g1, const float* __restrict__ b1,
    const float* __restrict__ g2, const float* __restrict__ b2,
    const float* __restrict__ g3, const float* __restrict__ b3,
    float* __restrict__ vf)
{
  __shared__ float A[3][CC], D[3][CC];
  int t = threadIdx.x;
  if (t < 240) {
    int set = t/CC, c = t%CC;
    const float* sp  = set==0? s2 : (set==1? s1 : s0);
    const float* gg  = set==0? g1 : (set==1? g2 : g3);
    const float* bbp = set==0? b1 : (set==1? b2 : b3);
    float s=0.f,q=0.f;
    for (int i=0;i<256;++i){ s+=sp[(i*2+0)*CC+c]; q+=sp[(i*2+1)*CC+c]; }
    float mean = s*(1.f/ROWS_Y);
    float var  = fmaf(-mean,mean,q*(1.f/ROWS_Y));
    float aa   = gg[c]*rsqrtf(var+1e-5f);
    A[set][c]=aa; D[set][c]=bbp[c]-mean*aa;
  }
  __syncthreads();
  for (size_t idx = (size_t)blockIdx.x*256 + t; idx < (size_t)ROWS_Y*CC; idx += (size_t)gridDim.x*256) {
    int c = (int)(idx % CC);
    float val = fmaf(v2[idx],A[0][c],D[0][c]) + fmaf(v1[idx],A[1][c],D[1][c]) + fmaf(v0[idx],A[2][c],D[2][c]);
    vf[idx] = val>0.f? val : expm1f(val);
  }
}

// ---------------- w[b,n] = sum_k mask[b,k] L[b,k,n] ----------------
__global__ __launch_bounds__(256) void k_w(
    const float* __restrict__ mask, const float* __restrict__ L, float* __restrict__ w)
{
  int bx = blockIdx.x;            // 32
  int b = bx >> 4, n0 = (bx & 15) * 64;
  int t = threadIdx.x;
  int ks = t >> 6;
  __shared__ float red[4][64];
  float acc=0.f;
  const float* Lb = L + (size_t)b*NN*NN;
  const float* mb = mask + b*NN;
  int n = n0 + (t & 63);
  for (int k = ks*256; k < ks*256+256; ++k)
    acc = fmaf(mb[k], Lb[(size_t)k*NN + n], acc);
  red[ks][t&63]=acc;
  __syncthreads();
  if (t < 64) w[b*NN + n0 + t] = red[0][t]+red[1][t]+red[2][t]+red[3][t];
}

// ---------------- pooled partials: p1 = sum mask*vf, p2 = sum w*vf ----------------
__global__ __launch_bounds__(256) void k_pool(
    const float* __restrict__ vf, const float* __restrict__ mask,
    const float* __restrict__ w, float* __restrict__ part)
{
  int bx = blockIdx.x;            // 16
  int b = bx >> 3, slab = bx & 7;
  int t = threadIdx.x, c = t%CC, rs = t/CC;
  __shared__ float st[3][2][CC];
  if (t<240) {
    float a1=0.f,a2=0.f;
    for (int r = rs; r < 128; r += 3) {
      int row = slab*128 + r;
      float val = vf[((size_t)b*NN + row)*CC + c];
      a1 = fmaf(mask[b*NN+row], val, a1);
      a2 = fmaf(w[b*NN+row],    val, a2);
    }
    st[rs][0][c]=a1; st[rs][1][c]=a2;
  }
  __syncthreads();
  if (t<CC) {
    part[((b*8+slab)*2+0)*CC+t] = st[0][0][t]+st[1][0][t]+st[2][0][t];
    part[((b*8+slab)*2+1)*CC+t] = st[0][1][t]+st[1][1][t]+st[2][1][t];
  }
}

// ---------------- out[b,co] = (p1@W0 + p2@W1)/msum + b2 ----------------
__global__ __launch_bounds__(256) void k_out(
    const float* __restrict__ part, const float* __restrict__ mask,
    const float* __restrict__ W0, const float* __restrict__ W1,
    const float* __restrict__ b2, float* __restrict__ outp)
{
  __shared__ float pl[2][2][CC];
  __shared__ float ms[2];
  int t = threadIdx.x;
  if (t < 160) {
    int b = t/CC, c = t%CC;
    float s1=0.f,s2=0.f;
    for (int slab=0; slab<8; ++slab){
      s1 += part[((b*8+slab)*2+0)*CC+c];
      s2 += part[((b*8+slab)*2+1)*CC+c];
    }
    pl[b][0][c]=s1; pl[b][1][c]=s2;
  }
  if (t>=160 && t<162) {
    int b=t-160; float s=0.f;
    for (int k=0;k<NN;++k) s += mask[b*NN+k];
    ms[b]=s;
  }
  __syncthreads();
  int b = t >> 7, co = t & 127;
  float acc = 0.f;
  #pragma unroll 8
  for (int c=0;c<CC;++c)
    acc += pl[b][0][c]*W0[c*128+co] + pl[b][1][c]*W1[c*128+co];
  outp[t] = acc/ms[b] + b2[co];
}

extern "C" void kernel_launch(void* const* d_in, const int* in_sizes, int n_in,
                              void* d_out, int out_size, void* d_ws, size_t ws_size,
                              hipStream_t stream)
{
  const float* inp  = (const float*)d_in[0];
  const float* L    = (const float*)d_in[1];
  const float* Di   = (const float*)d_in[2];
  const float* DiA  = (const float*)d_in[3];
  const float* mask = (const float*)d_in[4];
  const float* c1W0 = (const float*)d_in[5];
  const float* c1W1 = (const float*)d_in[6];
  const float* c1b  = (const float*)d_in[7];
  const float* bn0g = (const float*)d_in[8];
  const float* bn0b = (const float*)d_in[9];
  const float* fc0W = (const float*)d_in[10];
  const float* fc0b = (const float*)d_in[11];
  const float* bn1g = (const float*)d_in[12];
  const float* bn1b = (const float*)d_in[13];
  const float* fc1W = (const float*)d_in[14];
  const float* fc1b = (const float*)d_in[15];
  const float* fbn1g= (const float*)d_in[16];
  const float* fbn1b= (const float*)d_in[17];
  const float* fbn2g= (const float*)d_in[18];
  const float* fbn2b= (const float*)d_in[19];
  const float* fbn3g= (const float*)d_in[20];
  const float* fbn3b= (const float*)d_in[21];
  const float* c2W0 = (const float*)d_in[22];
  const float* c2W1 = (const float*)d_in[23];
  const float* c2b  = (const float*)d_in[24];

  float* ws = (float*)d_ws;
  size_t off = 0;
  auto alloc = [&](size_t n)->float* { float* p = ws + off; off += (n + 63) & ~(size_t)63; return p; };
  const size_t STFL = (size_t)1024*2*CC;   // stat buffers: up to 1024 slots
  float* vb[3];   for (int i=0;i<3;++i) vb[i]   = alloc((size_t)BB*NN*CC);
  float* fb[2];   for (int i=0;i<2;++i) fb[i]   = alloc((size_t)BB*FF*CC);
  float* Dv       = alloc((size_t)BB*FF*CC);
  float* Df       = alloc((size_t)BB*NN*CC);
  float* vstat[3];for (int i=0;i<3;++i) vstat[i]= alloc(STFL);
  float* fstat[2];for (int i=0;i<2;++i) fstat[i]= alloc(STFL);
  float* dvstat   = alloc(STFL);
  float* dfstat   = alloc(STFL);
  float* vf       = alloc((size_t)BB*NN*CC);
  float* wv       = alloc((size_t)BB*NN);
  float* part     = alloc((size_t)16*2*CC);
  const size_t nDi = (size_t)BB*(4*FF)*(4*NN);      // 67,108,864 elems each
  unsigned short* Dib  = (unsigned short*)alloc(nDi/2);
  unsigned short* DiAb = (unsigned short*)alloc(nDi/2);
  bool usebf = (off*sizeof(float) <= ws_size);

  hipMemsetAsync(fb[0],    0, (size_t)BB*FF*CC*4, stream);
  hipMemsetAsync(fb[1],    0, (size_t)BB*FF*CC*4, stream);
  hipMemsetAsync(vb[1],    0, (size_t)BB*NN*CC*4, stream);
  hipMemsetAsync(fstat[0], 0, (size_t)256*2*CC*4, stream);

  if (usebf) {
    k_cvt<<<4096,256,0,stream>>>(Di,  (unsigned int*)Dib,  nDi/8);
    k_cvt<<<4096,256,0,stream>>>(DiA, (unsigned int*)DiAb, nDi/8);
  }

  k_conv1<<<128,256,0,stream>>>(inp, L, c1W0, c1W1, c1b, vb[0], vstat[0]);

  int cur=0, p1=1, p2=2, fcur=0, fs=0;
  for (int it=0; it<NB_; ++it) {
    if (usebf) k_dirac<4,unsigned short><<<dim3(512,2),256,0,stream>>>(Dib, vb[cur], Dv, dvstat, 4*FF, 4*NN);
    else       k_dirac<4,float         ><<<dim3(512,2),256,0,stream>>>(Di,  vb[cur], Dv, dvstat, 4*FF, 4*NN);
    k_fc<<<256,256,0,stream>>>(fb[fcur], Dv, fstat[fs],256, dvstat,1024,
        bn0g+(size_t)it*C2, bn0b+(size_t)it*C2, fc0W+(size_t)it*C2*CC, fc0b+(size_t)it*CC,
        fb[1-fcur], fb[1-fcur], fstat[1-fs], ROWS_X, 1.f/ROWS_X);
    fcur = 1-fcur; fs = 1-fs;
    if (usebf) k_dirac<4,unsigned short><<<dim3(256,2),256,0,stream>>>(DiAb, fb[fcur], Df, dfstat, 4*NN, 4*FF);
    else       k_dirac<4,float         ><<<dim3(256,2),256,0,stream>>>(DiA,  fb[fcur], Df, dfstat, 4*NN, 4*FF);
    k_fc<<<256,256,0,stream>>>(vb[cur], Df, vstat[cur],(it==0?128:256), dfstat,512,
        bn1g+(size_t)it*C2, bn1b+(size_t)it*C2, fc1W+(size_t)it*C2*CC, fc1b+(size_t)it*CC,
        vb[p1], vb[p2], vstat[p2], ROWS_Y, 1.f/ROWS_Y);
    int tmp=p2; p2=p1; p1=cur; cur=tmp;
  }

  k_final<<<128,256,0,stream>>>(vb[cur],vb[p1],vb[p2], vstat[cur],vstat[p1],vstat[p2],
      fbn1g,fbn1b,fbn2g,fbn2b,fbn3g,fbn3b, vf);
  k_w<<<32,256,0,stream>>>(mask, L, wv);
  k_pool<<<16,256,0,stream>>>(vf, mask, wv, part);
  k_out<<<1,256,0,stream>>>(part, mask, c2W0, c2W1, c2b, (float*)d_out);
}

// Round 8
// 3834.660 us; speedup vs baseline: 4.3717x; 2.3158x over previous
//
#include <hip/hip_runtime.h>
#include <cstdint>

#define BB 2
#define NN 1024
#define FF 2048
#define CC 80
#define C2 160
#define NB_ 15
#define ROWS_X (BB*FF)   /* 4096 */
#define ROWS_Y (BB*NN)   /* 2048 */

// ---------------- conv1: v = in@W0 + (L@in)@W1 + b, + v-stats partials (128 slots) ----------------
__global__ __launch_bounds__(256) void k_conv1(
    const float* __restrict__ inp, const float* __restrict__ L,
    const float* __restrict__ W0, const float* __restrict__ W1,
    const float* __restrict__ bias, float* __restrict__ v,
    float* __restrict__ vstat)
{
  int bx = blockIdx.x;            // 128 = 2 batches x 64 row-blocks
  int b = bx >> 6, rb = bx & 63;
  int row0 = rb * 16;
  __shared__ float red[256][3];
  __shared__ float lx[16][3];
  __shared__ float st[16][2][CC];
  int t = threadIdx.x;
  int rloc = t >> 4, sl = t & 15;
  const float* Lrow = L + ((size_t)b*NN + row0 + rloc) * NN;
  const float* ipb  = inp + (size_t)b*NN*3;
  float a0=0.f,a1=0.f,a2=0.f;
  for (int m = sl; m < NN; m += 16) {
    float lv = Lrow[m];
    a0 = fmaf(lv, ipb[m*3+0], a0);
    a1 = fmaf(lv, ipb[m*3+1], a1);
    a2 = fmaf(lv, ipb[m*3+2], a2);
  }
  red[t][0]=a0; red[t][1]=a1; red[t][2]=a2;
  __syncthreads();
  if (t < 48) {
    int row = t/3, ci = t%3;
    float s=0.f;
    for (int s2=0; s2<16; ++s2) s += red[row*16+s2][ci];
    lx[row][ci]=s;
  }
  __syncthreads();
  for (int o = t; o < 16*CC; o += 256) {
    int row = o/CC, c = o%CC;
    const float* ir = inp + ((size_t)b*NN + row0 + row)*3;
    float val = bias[c];
    #pragma unroll
    for (int ci=0; ci<3; ++ci)
      val += ir[ci]*W0[ci*CC+c] + lx[row][ci]*W1[ci*CC+c];
    v[((size_t)b*NN + row0 + row)*CC + c] = val;
    st[row][0][c] = val;
    st[row][1][c] = val*val;
  }
  __syncthreads();
  if (t < CC) {
    float s=0.f,q=0.f;
    for (int row=0; row<16; ++row){ s+=st[row][0][t]; q+=st[row][1][t]; }
    vstat[(bx*2+0)*CC + t] = s;
    vstat[(bx*2+1)*CC + t] = q;
  }
}

// ---------------- f32 -> bf16 (RNE) bulk convert: 8 elems/thread/iter ----------------
__global__ __launch_bounds__(256) void k_cvt(
    const float* __restrict__ src, unsigned int* __restrict__ dst, size_t n8)
{
  size_t i = (size_t)blockIdx.x*256 + threadIdx.x;
  size_t stride = (size_t)gridDim.x*256;
  for (; i < n8; i += stride) {
    const uint4* s = (const uint4*)src + i*2;
    uint4 u0 = s[0], u1 = s[1];
    uint4 o;
    #define CV(a,b) ((((a) + 0x7FFFu + (((a)>>16)&1u)) >> 16) | ((((b) + 0x7FFFu + (((b)>>16)&1u)) >> 16) << 16))
    o.x = CV(u0.x,u0.y); o.y = CV(u0.z,u0.w);
    o.z = CV(u1.x,u1.y); o.w = CV(u1.z,u1.w);
    #undef CV
    ((uint4*)dst)[i] = o;
  }
}

// ---------------- A-fragment: 4 consecutive elems, bf16 or f32 ----------------
__device__ __forceinline__ float4 bf4_to_f4(uint2 r) {
  float4 f;
  ((unsigned&)f.x) = r.x << 16;
  ((unsigned&)f.y) = r.x & 0xFFFF0000u;
  ((unsigned&)f.z) = r.y << 16;
  ((unsigned&)f.w) = r.y & 0xFFFF0000u;
  return f;
}
template<typename AT> struct AFr;
template<> struct AFr<unsigned short> {
  uint2 v;
  __device__ __forceinline__ void load(const unsigned short* p){ v = *(const uint2*)p; }
  __device__ __forceinline__ float4 get() const { return bf4_to_f4(v); }
};
template<> struct AFr<float> {
  float4 v;
  __device__ __forceinline__ void load(const float* p){ v = *(const float4*)p; }
  __device__ __forceinline__ float4 get() const { return v; }
};

// ---------------- Dirac: y[m,q] = sum_k A[m,k] * x[k,q] (q=0..19), + y-stats partials ----
// Pipelined streamer: chunk=256 k, double-buffered transposed x in LDS
// (conflict-free ds_read_b128), A prefetched one chunk ahead. DR=4 rows/wave.
// acc[][] only ever indexed with compile-time constants (rule #20).
template<int DR, typename AT>
__global__ __launch_bounds__(256) __attribute__((amdgpu_waves_per_eu(2,2)))
void k_dirac(
    const AT* __restrict__ A, const float* __restrict__ x,
    float* __restrict__ y, float* __restrict__ stat, int M, int K)
{
  static_assert(DR == 4, "stats channel mapping assumes DR==4");
  int b = blockIdx.y;
  A += (size_t)b*M*K; x += (size_t)b*(size_t)K*20; y += (size_t)b*(size_t)M*20;
  __shared__ float xs[2][20][256];
  __shared__ float stS[4][CC];
  __shared__ float stQ[4][CC];
  int t = threadIdx.x, lane = t & 63, w = t >> 6;
  int row0 = blockIdx.x*(4*DR) + w*DR;
  float acc[DR][20];
  #pragma unroll
  for (int r=0;r<DR;++r)
    #pragma unroll
    for (int q=0;q<20;++q) acc[r][q]=0.f;

  const float4* xv = (const float4*)x;   // x row k = 5 float4s at k*5
  int nchunk = K >> 8;
  const AT* Abase = A + (size_t)row0*K + (lane<<2);

  { // stage chunk 0 (transposed)
    float4 s0[5];
    #pragma unroll
    for (int i=0;i<5;++i) s0[i] = xv[(size_t)t*5 + i];
    #pragma unroll
    for (int i=0;i<5;++i) {
      xs[0][4*i+0][t]=s0[i].x; xs[0][4*i+1][t]=s0[i].y;
      xs[0][4*i+2][t]=s0[i].z; xs[0][4*i+3][t]=s0[i].w;
    }
  }
  AFr<AT> a[DR];
  #pragma unroll
  for (int r=0;r<DR;++r) a[r].load(Abase + (size_t)r*K);
  __syncthreads();

  for (int c=0; c<nchunk; ++c) {
    int cur = c & 1;
    bool more = (c+1 < nchunk);
    float4 st[5];
    if (more) {                           // issue next x-stage loads early
      size_t kb = (size_t)(c+1)*256 + t;
      #pragma unroll
      for (int i=0;i<5;++i) st[i] = xv[kb*5 + i];
    }
    float4 af[DR];                        // convert current A, then reload a
    #pragma unroll
    for (int r=0;r<DR;++r) af[r] = a[r].get();
    if (more) {
      const AT* An = Abase + (size_t)(c+1)*256;
      #pragma unroll
      for (int r=0;r<DR;++r) a[r].load(An + (size_t)r*K);
    }
    #pragma unroll
    for (int q=0;q<20;++q) {
      float4 xq = *(const float4*)(&xs[cur][q][lane<<2]);
      #pragma unroll
      for (int r=0;r<DR;++r) {
        acc[r][q] = fmaf(af[r].x, xq.x, acc[r][q]);
        acc[r][q] = fmaf(af[r].y, xq.y, acc[r][q]);
        acc[r][q] = fmaf(af[r].z, xq.z, acc[r][q]);
        acc[r][q] = fmaf(af[r].w, xq.w, acc[r][q]);
      }
    }
    if (more) {                           // publish next buffer
      #pragma unroll
      for (int i=0;i<5;++i) {
        xs[cur^1][4*i+0][t]=st[i].x; xs[cur^1][4*i+1][t]=st[i].y;
        xs[cur^1][4*i+2][t]=st[i].z; xs[cur^1][4*i+3][t]=st[i].w;
      }
    }
    __syncthreads();
  }

  #pragma unroll
  for (int r=0;r<DR;++r) {
    #pragma unroll
    for (int q=0;q<20;++q) {
      float s = acc[r][q];
      s += __shfl_xor(s, 1);
      s += __shfl_xor(s, 2);
      s += __shfl_xor(s, 4);
      s += __shfl_xor(s, 8);
      s += __shfl_xor(s, 16);
      s += __shfl_xor(s, 32);
      acc[r][q]=s;                        // all lanes now hold the full sum
    }
    if (lane==0) {
      float4* yp = (float4*)(y + (size_t)(row0+r)*20);
      yp[0] = make_float4(acc[r][0],acc[r][1],acc[r][2],acc[r][3]);
      yp[1] = make_float4(acc[r][4],acc[r][5],acc[r][6],acc[r][7]);
      yp[2] = make_float4(acc[r][8],acc[r][9],acc[r][10],acc[r][11]);
      yp[3] = make_float4(acc[r][12],acc[r][13],acc[r][14],acc[r][15]);
      yp[4] = make_float4(acc[r][16],acc[r][17],acc[r][18],acc[r][19]);
    }
  }
  // stats: post-butterfly all lanes hold identical sums; lane 0 per wave
  // writes its wave's 80 channels with COMPILE-TIME indices only.
  if (lane == 0) {
    #pragma unroll
    for (int r=0;r<DR;++r)
      #pragma unroll
      for (int q=0;q<20;++q) {
        float v0 = acc[r][q];
        stS[w][r*20+q] = v0;
        stQ[w][r*20+q] = v0*v0;
      }
  }
  __syncthreads();
  int slot = blockIdx.y*gridDim.x + blockIdx.x;
  if (t < 80) {
    stat[((size_t)slot*2+0)*CC + t] = stS[0][t]+stS[1][t]+stS[2][t]+stS[3][t];
  } else if (t < 160) {
    int c2=t-80;
    stat[((size_t)slot*2+1)*CC + c2] = stQ[0][c2]+stQ[1][c2]+stQ[2][c2]+stQ[3][c2];
  }
}

// ---------------- fused BN(fold)+FC+ELU+residual, + output-stats partials (grid slots) ----
// Stats prologue BATCHED (8-wide load groups): serial `s += load` loops keep
// only 1 load in flight -> round-7 PMC showed 308us @ 23GB/s, VALUBusy 3%.
__global__ __launch_bounds__(256) void k_fc(
    const float* __restrict__ p1, const float* __restrict__ p2,
    const float* __restrict__ sp1, int ns1,
    const float* __restrict__ sp2, int ns2,
    const float* __restrict__ g, const float* __restrict__ bb,
    const float* __restrict__ W, const float* __restrict__ cb,
    const float* add, float* out,
    float* __restrict__ statout, int rows, float invrows)
{
  __shared__ float Wl[C2*CC];
  __shared__ float ad[2][C2];
  __shared__ float bpl[CC];
  __shared__ float xsh[3][C2];
  __shared__ float st[3][2][CC];
  int t = threadIdx.x;
  if (t < C2) {
    int c = (t<CC)? t : t-CC;
    const float* sp = (t<CC)? sp1 : sp2;
    int ns = (t<CC)? ns1 : ns2;
    float s=0.f,q=0.f;
    int i=0;
    for (; i+8<=ns; i+=8) {
      float vs[8], vq[8];
      #pragma unroll
      for (int j=0;j<8;++j){ vs[j]=sp[((i+j)*2+0)*CC+c]; vq[j]=sp[((i+j)*2+1)*CC+c]; }
      #pragma unroll
      for (int j=0;j<8;++j){ s+=vs[j]; q+=vq[j]; }
    }
    for (; i<ns; ++i){ s+=sp[(i*2+0)*CC+c]; q+=sp[(i*2+1)*CC+c]; }
    float mean = s*invrows;
    float var  = fmaf(-mean, mean, q*invrows);
    float aa   = g[t]*rsqrtf(var + 1e-5f);
    ad[0][t]=aa; ad[1][t]= bb[t] - mean*aa;
  }
  __syncthreads();
  for (int i=t;i<C2*CC;i+=256) Wl[i] = W[i]*ad[0][i/CC];
  if (t < CC) {
    float s = cb[t];
    for (int c2=0;c2<C2;c2+=8) {
      float wv[8];
      #pragma unroll
      for (int j=0;j<8;++j) wv[j] = W[(c2+j)*CC+t];
      #pragma unroll
      for (int j=0;j<8;++j) s = fmaf(ad[1][c2+j], wv[j], s);
    }
    bpl[t]=s;
  }
  __syncthreads();
  int c = t%CC, rs = t/CC;
  bool act = t < 240;
  float ssum=0.f, ssq=0.f;
  for (int r0 = blockIdx.x*3; r0 < rows; r0 += gridDim.x*3) {
    int row = r0 + rs;
    bool ok = act && row < rows;
    if (ok) {
      xsh[rs][c]    = p1[(size_t)row*CC+c];
      xsh[rs][CC+c] = p2[(size_t)row*CC+c];
    }
    __syncthreads();
    if (ok) {
      float acc = bpl[c];
      #pragma unroll 8
      for (int c2=0;c2<C2;++c2) acc = fmaf(xsh[rs][c2], Wl[c2*CC+c], acc);
      acc = acc>0.f ? acc : expm1f(acc);
      acc += add[(size_t)row*CC+c];
      out[(size_t)row*CC+c] = acc;
      ssum += acc; ssq = fmaf(acc,acc,ssq);
    }
    __syncthreads();
  }
  if (act){ st[rs][0][c]=ssum; st[rs][1][c]=ssq; }
  __syncthreads();
  if (t<CC){
    statout[(blockIdx.x*2+0)*CC+t] = st[0][0][t]+st[1][0][t]+st[2][0][t];
    statout[(blockIdx.x*2+1)*CC+t] = st[0][1][t]+st[1][1][t]+st[2][1][t];
  }
}

// ---------------- final: vf = elu(bn1(v2)+bn2(v1)+bn3(v0)) ----------------
__global__ __launch_bounds__(256) void k_final(
    const float* __restrict__ v2, const float* __restrict__ v1, const float* __restrict__ v0,
    const float* __restrict__ s2, const float* __restrict__ s1, const float* __restrict__ s0,
    const float* __restrict__ g1, const float* __restrict__ b1,
    const float* __restrict__ g2, const float* __restrict__ b2,
    const float* __restrict__ g3, const float* __restrict__ b3,
    float* __restrict__ vf)
{
  __shared__ float A[3][CC], D[3][CC];
  int t = threadIdx.x;
  if (t < 240) {
    int set = t/CC, c = t%CC;
    const float* sp  = set==0? s2 : (set==1? s1 : s0);
    const float* gg  = set==0? g1 : (set==1? g2 : g3);
    const float* bbp = set==0? b1 : (set==1? b2 : b3);
    float s=0.f,q=0.f;
    for (int i=0;i<256;i+=8){
      float vs[8], vq[8];
      #pragma unroll
      for (int j=0;j<8;++j){ vs[j]=sp[((i+j)*2+0)*CC+c]; vq[j]=sp[((i+j)*2+1)*CC+c]; }
      #pragma unroll
      for (int j=0;j<8;++j){ s+=vs[j]; q+=vq[j]; }
    }
    float mean = s*(1.f/ROWS_Y);
    float var  = fmaf(-mean,mean,q*(1.f/ROWS_Y));
    float aa   = gg[c]*rsqrtf(var+1e-5f);
    A[set][c]=aa; D[set][c]=bbp[c]-mean*aa;
  }
  __syncthreads();
  for (size_t idx = (size_t)blockIdx.x*256 + t; idx < (size_t)ROWS_Y*CC; idx += (size_t)gridDim.x*256) {
    int c = (int)(idx % CC);
    float val = fmaf(v2[idx],A[0][c],D[0][c]) + fmaf(v1[idx],A[1][c],D[1][c]) + fmaf(v0[idx],A[2][c],D[2][c]);
    vf[idx] = val>0.f? val : expm1f(val);
  }
}

// ---------------- w[b,n] = sum_k mask[b,k] L[b,k,n] ----------------
__global__ __launch_bounds__(256) void k_w(
    const float* __restrict__ mask, const float* __restrict__ L, float* __restrict__ w)
{
  int bx = blockIdx.x;            // 32
  int b = bx >> 4, n0 = (bx & 15) * 64;
  int t = threadIdx.x;
  int ks = t >> 6;
  __shared__ float red[4][64];
  float acc=0.f;
  const float* Lb = L + (size_t)b*NN*NN;
  const float* mb = mask + b*NN;
  int n = n0 + (t & 63);
  for (int k = ks*256; k < ks*256+256; k+=8) {
    float mv[8], lv[8];
    #pragma unroll
    for (int j=0;j<8;++j){ mv[j]=mb[k+j]; lv[j]=Lb[(size_t)(k+j)*NN + n]; }
    #pragma unroll
    for (int j=0;j<8;++j) acc = fmaf(mv[j], lv[j], acc);
  }
  red[ks][t&63]=acc;
  __syncthreads();
  if (t < 64) w[b*NN + n0 + t] = red[0][t]+red[1][t]+red[2][t]+red[3][t];
}

// ---------------- pooled partials: p1 = sum mask*vf, p2 = sum w*vf ----------------
__global__ __launch_bounds__(256) void k_pool(
    const float* __restrict__ vf, const float* __restrict__ mask,
    const float* __restrict__ w, float* __restrict__ part)
{
  int bx = blockIdx.x;            // 16
  int b = bx >> 3, slab = bx & 7;
  int t = threadIdx.x, c = t%CC, rs = t/CC;
  __shared__ float st[3][2][CC];
  if (t<240) {
    float a1=0.f,a2=0.f;
    for (int r = rs; r < 128; r += 3) {
      int row = slab*128 + r;
      float val = vf[((size_t)b*NN + row)*CC + c];
      a1 = fmaf(mask[b*NN+row], val, a1);
      a2 = fmaf(w[b*NN+row],    val, a2);
    }
    st[rs][0][c]=a1; st[rs][1][c]=a2;
  }
  __syncthreads();
  if (t<CC) {
    part[((b*8+slab)*2+0)*CC+t] = st[0][0][t]+st[1][0][t]+st[2][0][t];
    part[((b*8+slab)*2+1)*CC+t] = st[0][1][t]+st[1][1][t]+st[2][1][t];
  }
}

// ---------------- out[b,co] = (p1@W0 + p2@W1)/msum + b2 ----------------
__global__ __launch_bounds__(256) void k_out(
    const float* __restrict__ part, const float* __restrict__ mask,
    const float* __restrict__ W0, const float* __restrict__ W1,
    const float* __restrict__ b2, float* __restrict__ outp)
{
  __shared__ float pl[2][2][CC];
  __shared__ float msred[2][128];
  __shared__ float ms[2];
  int t = threadIdx.x;
  { // mask sums: all 256 threads, batched
    int b = t >> 7, k0 = t & 127;
    float m[8];
    #pragma unroll
    for (int j=0;j<8;++j) m[j] = mask[b*NN + k0 + j*128];
    msred[b][k0] = ((m[0]+m[1])+(m[2]+m[3]))+((m[4]+m[5])+(m[6]+m[7]));
  }
  if (t < 160) {
    int b = t/CC, c = t%CC;
    float v1[8], v2[8];
    #pragma unroll
    for (int slab=0; slab<8; ++slab){
      v1[slab] = part[((b*8+slab)*2+0)*CC+c];
      v2[slab] = part[((b*8+slab)*2+1)*CC+c];
    }
    float s1=0.f,s2=0.f;
    #pragma unroll
    for (int slab=0;slab<8;++slab){ s1+=v1[slab]; s2+=v2[slab]; }
    pl[b][0][c]=s1; pl[b][1][c]=s2;
  }
  __syncthreads();
  if (t < 2) {
    float s=0.f;
    for (int k=0;k<128;++k) s += msred[t][k];
    ms[t]=s;
  }
  __syncthreads();
  int b = t >> 7, co = t & 127;
  float acc = 0.f;
  for (int c=0;c<CC;c+=8) {
    float w0[8], w1[8];
    #pragma unroll
    for (int j=0;j<8;++j){ w0[j]=W0[(c+j)*128+co]; w1[j]=W1[(c+j)*128+co]; }
    #pragma unroll
    for (int j=0;j<8;++j) acc += pl[b][0][c+j]*w0[j] + pl[b][1][c+j]*w1[j];
  }
  outp[t] = acc/ms[b] + b2[co];
}

extern "C" void kernel_launch(void* const* d_in, const int* in_sizes, int n_in,
                              void* d_out, int out_size, void* d_ws, size_t ws_size,
                              hipStream_t stream)
{
  const float* inp  = (const float*)d_in[0];
  const float* L    = (const float*)d_in[1];
  const float* Di   = (const float*)d_in[2];
  const float* DiA  = (const float*)d_in[3];
  const float* mask = (const float*)d_in[4];
  const float* c1W0 = (const float*)d_in[5];
  const float* c1W1 = (const float*)d_in[6];
  const float* c1b  = (const float*)d_in[7];
  const float* bn0g = (const float*)d_in[8];
  const float* bn0b = (const float*)d_in[9];
  const float* fc0W = (const float*)d_in[10];
  const float* fc0b = (const float*)d_in[11];
  const float* bn1g = (const float*)d_in[12];
  const float* bn1b = (const float*)d_in[13];
  const float* fc1W = (const float*)d_in[14];
  const float* fc1b = (const float*)d_in[15];
  const float* fbn1g= (const float*)d_in[16];
  const float* fbn1b= (const float*)d_in[17];
  const float* fbn2g= (const float*)d_in[18];
  const float* fbn2b= (const float*)d_in[19];
  const float* fbn3g= (const float*)d_in[20];
  const float* fbn3b= (const float*)d_in[21];
  const float* c2W0 = (const float*)d_in[22];
  const float* c2W1 = (const float*)d_in[23];
  const float* c2b  = (const float*)d_in[24];

  float* ws = (float*)d_ws;
  size_t off = 0;
  auto alloc = [&](size_t n)->float* { float* p = ws + off; off += (n + 63) & ~(size_t)63; return p; };
  const size_t STFL = (size_t)1024*2*CC;   // stat buffers: up to 1024 slots
  float* vb[3];   for (int i=0;i<3;++i) vb[i]   = alloc((size_t)BB*NN*CC);
  float* fb[2];   for (int i=0;i<2;++i) fb[i]   = alloc((size_t)BB*FF*CC);
  float* Dv       = alloc((size_t)BB*FF*CC);
  float* Df       = alloc((size_t)BB*NN*CC);
  float* vstat[3];for (int i=0;i<3;++i) vstat[i]= alloc(STFL);
  float* fstat[2];for (int i=0;i<2;++i) fstat[i]= alloc(STFL);
  float* dvstat   = alloc(STFL);
  float* dfstat   = alloc(STFL);
  float* vf       = alloc((size_t)BB*NN*CC);
  float* wv       = alloc((size_t)BB*NN);
  float* part     = alloc((size_t)16*2*CC);
  const size_t nDi = (size_t)BB*(4*FF)*(4*NN);      // 67,108,864 elems each
  unsigned short* Dib  = (unsigned short*)alloc(nDi/2);
  unsigned short* DiAb = (unsigned short*)alloc(nDi/2);
  bool usebf = (off*sizeof(float) <= ws_size);

  hipMemsetAsync(fb[0],    0, (size_t)BB*FF*CC*4, stream);
  hipMemsetAsync(fb[1],    0, (size_t)BB*FF*CC*4, stream);
  hipMemsetAsync(vb[1],    0, (size_t)BB*NN*CC*4, stream);
  hipMemsetAsync(fstat[0], 0, (size_t)256*2*CC*4, stream);

  if (usebf) {
    k_cvt<<<4096,256,0,stream>>>(Di,  (unsigned int*)Dib,  nDi/8);
    k_cvt<<<4096,256,0,stream>>>(DiA, (unsigned int*)DiAb, nDi/8);
  }

  k_conv1<<<128,256,0,stream>>>(inp, L, c1W0, c1W1, c1b, vb[0], vstat[0]);

  int cur=0, p1=1, p2=2, fcur=0, fs=0;
  for (int it=0; it<NB_; ++it) {
    if (usebf) k_dirac<4,unsigned short><<<dim3(512,2),256,0,stream>>>(Dib, vb[cur], Dv, dvstat, 4*FF, 4*NN);
    else       k_dirac<4,float         ><<<dim3(512,2),256,0,stream>>>(Di,  vb[cur], Dv, dvstat, 4*FF, 4*NN);
    k_fc<<<256,256,0,stream>>>(fb[fcur], Dv, fstat[fs],256, dvstat,1024,
        bn0g+(size_t)it*C2, bn0b+(size_t)it*C2, fc0W+(size_t)it*C2*CC, fc0b+(size_t)it*CC,
        fb[1-fcur], fb[1-fcur], fstat[1-fs], ROWS_X, 1.f/ROWS_X);
    fcur = 1-fcur; fs = 1-fs;
    if (usebf) k_dirac<4,unsigned short><<<dim3(256,2),256,0,stream>>>(DiAb, fb[fcur], Df, dfstat, 4*NN, 4*FF);
    else       k_dirac<4,float         ><<<dim3(256,2),256,0,stream>>>(DiA,  fb[fcur], Df, dfstat, 4*NN, 4*FF);
    k_fc<<<256,256,0,stream>>>(vb[cur], Df, vstat[cur],(it==0?128:256), dfstat,512,
        bn1g+(size_t)it*C2, bn1b+(size_t)it*C2, fc1W+(size_t)it*C2*CC, fc1b+(size_t)it*CC,
        vb[p1], vb[p2], vstat[p2], ROWS_Y, 1.f/ROWS_Y);
    int tmp=p2; p2=p1; p1=cur; cur=tmp;
  }

  k_final<<<128,256,0,stream>>>(vb[cur],vb[p1],vb[p2], vstat[cur],vstat[p1],vstat[p2],
      fbn1g,fbn1b,fbn2g,fbn2b,fbn3g,fbn3b, vf);
  k_w<<<32,256,0,stream>>>(mask, L, wv);
  k_pool<<<16,256,0,stream>>>(vf, mask, wv, part);
  k_out<<<1,256,0,stream>>>(part, mask, c2W0, c2W1, c2b, (float*)d_out);
}

// Round 9
// 2750.012 us; speedup vs baseline: 6.0960x; 1.3944x over previous
//
#include <hip/hip_runtime.h>
#include <cstdint>

#define BB 2
#define NN 1024
#define FF 2048
#define CC 80
#define C2 160
#define NB_ 15
#define ROWS_X (BB*FF)   /* 4096 */
#define ROWS_Y (BB*NN)   /* 2048 */

typedef __attribute__((ext_vector_type(8))) _Float16 half8;
typedef __attribute__((ext_vector_type(4))) float f32x4;

// ---------------- conv1: v = in@W0 + (L@in)@W1 + b, + v-stats partials (128 slots) ----------------
__global__ __launch_bounds__(256) void k_conv1(
    const float* __restrict__ inp, const float* __restrict__ L,
    const float* __restrict__ W0, const float* __restrict__ W1,
    const float* __restrict__ bias, float* __restrict__ v,
    float* __restrict__ vstat)
{
  int bx = blockIdx.x;            // 128 = 2 batches x 64 row-blocks
  int b = bx >> 6, rb = bx & 63;
  int row0 = rb * 16;
  __shared__ float red[256][3];
  __shared__ float lx[16][3];
  __shared__ float st[16][2][CC];
  int t = threadIdx.x;
  int rloc = t >> 4, sl = t & 15;
  const float* Lrow = L + ((size_t)b*NN + row0 + rloc) * NN;
  const float* ipb  = inp + (size_t)b*NN*3;
  float a0=0.f,a1=0.f,a2=0.f;
  for (int m = sl; m < NN; m += 16) {
    float lv = Lrow[m];
    a0 = fmaf(lv, ipb[m*3+0], a0);
    a1 = fmaf(lv, ipb[m*3+1], a1);
    a2 = fmaf(lv, ipb[m*3+2], a2);
  }
  red[t][0]=a0; red[t][1]=a1; red[t][2]=a2;
  __syncthreads();
  if (t < 48) {
    int row = t/3, ci = t%3;
    float s=0.f;
    for (int s2=0; s2<16; ++s2) s += red[row*16+s2][ci];
    lx[row][ci]=s;
  }
  __syncthreads();
  for (int o = t; o < 16*CC; o += 256) {
    int row = o/CC, c = o%CC;
    const float* ir = inp + ((size_t)b*NN + row0 + row)*3;
    float val = bias[c];
    #pragma unroll
    for (int ci=0; ci<3; ++ci)
      val += ir[ci]*W0[ci*CC+c] + lx[row][ci]*W1[ci*CC+c];
    v[((size_t)b*NN + row0 + row)*CC + c] = val;
    st[row][0][c] = val;
    st[row][1][c] = val*val;
  }
  __syncthreads();
  if (t < CC) {
    float s=0.f,q=0.f;
    for (int row=0; row<16; ++row){ s+=st[row][0][t]; q+=st[row][1][t]; }
    vstat[(bx*2+0)*CC + t] = s;
    vstat[(bx*2+1)*CC + t] = q;
  }
}

// ---------------- f32 -> fp16 (RNE) bulk convert: 8 elems/thread/iter ----------------
__device__ __forceinline__ unsigned pkh(float a, float b){
  _Float16 ha = (_Float16)a, hb = (_Float16)b;
  unsigned short ua = __builtin_bit_cast(unsigned short, ha);
  unsigned short ub = __builtin_bit_cast(unsigned short, hb);
  return (unsigned)ua | ((unsigned)ub << 16);
}
__global__ __launch_bounds__(256) void k_cvt(
    const float* __restrict__ src, uint4* __restrict__ dst, size_t n8)
{
  size_t i = (size_t)blockIdx.x*256 + threadIdx.x;
  size_t stride = (size_t)gridDim.x*256;
  for (; i < n8; i += stride) {
    const float4* s = (const float4*)src + i*2;
    float4 f0 = s[0], f1 = s[1];
    uint4 o;
    o.x = pkh(f0.x,f0.y); o.y = pkh(f0.z,f0.w);
    o.z = pkh(f1.x,f1.y); o.w = pkh(f1.z,f1.w);
    dst[i] = o;
  }
}

// ---------------- MFMA Dirac: y[M,20] = A[M,K](fp16) @ x[K,20], + y-stats ----------------
// Per wave: 16-row tile, full K. A-frag direct from global (lane: row=l%16,
// k=8*(l>>4)); x staged per 256-k chunk into LDS fp16 transposed xT[32][264]
// (rows 20..31 zero -> 2nd col-tile cols 4..15 exactly 0; +8 pad -> 4-bank
// offset, conflict-free ds_read_b128). C/D layout (m89): col=lane&15,
// row=4*(lane>>4)+reg. Channel = j*20+col. acc only const-indexed (rule #20).
__global__ __launch_bounds__(256) __attribute__((amdgpu_waves_per_eu(2,2)))
void k_dirac_mfma(
    const _Float16* __restrict__ A, const float* __restrict__ x,
    float* __restrict__ y, float* __restrict__ stat, int M, int K)
{
  int b = blockIdx.y;
  A += (size_t)b*M*K; x += (size_t)b*(size_t)K*20; y += (size_t)b*(size_t)M*20;
  __shared__ _Float16 xT[2][32][264];
  __shared__ float stS[4][CC], stQ[4][CC];
  int t = threadIdx.x, lane = t & 63, w = t >> 6;
  int row0 = blockIdx.x*64 + w*16;
  int cl = lane & 15, cg = lane >> 4;

  f32x4 acc0 = {0.f,0.f,0.f,0.f}, acc1 = {0.f,0.f,0.f,0.f};
  const float4* xv = (const float4*)x;     // x row k = 5 float4s
  int nchunk = K >> 8;
  const _Float16* Abase = A + (size_t)(row0 + cl)*K + cg*8;

  // zero pad rows 20..31 of both buffers (never touched by staging)
  for (int i = t; i < 2*12*264; i += 256) {
    int bb = i/(12*264), rem = i - bb*(12*264);
    xT[bb][20 + rem/264][rem%264] = (_Float16)0.f;
  }
  { // stage chunk 0
    float4 s0[5];
    #pragma unroll
    for (int i=0;i<5;++i) s0[i] = xv[(size_t)t*5 + i];
    #pragma unroll
    for (int i=0;i<5;++i) {
      xT[0][4*i+0][t]=(_Float16)s0[i].x; xT[0][4*i+1][t]=(_Float16)s0[i].y;
      xT[0][4*i+2][t]=(_Float16)s0[i].z; xT[0][4*i+3][t]=(_Float16)s0[i].w;
    }
  }
  half8 a_cur[8];
  #pragma unroll
  for (int ks=0;ks<8;++ks) a_cur[ks] = *(const half8*)(Abase + ks*32);
  __syncthreads();

  for (int c=0; c<nchunk; ++c) {
    int cur = c & 1;
    bool more = (c+1 < nchunk);
    float4 st5[5];
    half8 a_nxt[8];
    if (more) {                            // issue next-chunk loads early
      size_t kb = (size_t)(c+1)*256 + t;
      #pragma unroll
      for (int i=0;i<5;++i) st5[i] = xv[kb*5 + i];
      const _Float16* An = Abase + (size_t)(c+1)*256;
      #pragma unroll
      for (int ks=0;ks<8;++ks) a_nxt[ks] = *(const half8*)(An + ks*32);
    }
    #pragma unroll
    for (int ks=0;ks<8;++ks) {
      half8 b0 = *(const half8*)(&xT[cur][cl     ][ks*32 + cg*8]);
      half8 b1 = *(const half8*)(&xT[cur][16 + cl][ks*32 + cg*8]);
      acc0 = __builtin_amdgcn_mfma_f32_16x16x32_f16(a_cur[ks], b0, acc0, 0,0,0);
      acc1 = __builtin_amdgcn_mfma_f32_16x16x32_f16(a_cur[ks], b1, acc1, 0,0,0);
    }
    if (more) {                            // publish next buffer, rotate A
      #pragma unroll
      for (int i=0;i<5;++i) {
        xT[cur^1][4*i+0][t]=(_Float16)st5[i].x; xT[cur^1][4*i+1][t]=(_Float16)st5[i].y;
        xT[cur^1][4*i+2][t]=(_Float16)st5[i].z; xT[cur^1][4*i+3][t]=(_Float16)st5[i].w;
      }
      #pragma unroll
      for (int ks=0;ks<8;++ks) a_cur[ks] = a_nxt[ks];
    }
    __syncthreads();
  }

  // epilogue: y-write + stats. D: row = row0+4*cg+j, col = cl (tile0) / 16+cl (tile1)
  #pragma unroll
  for (int j=0;j<4;++j) {
    float v = acc0[j];
    y[(size_t)(row0 + 4*cg + j)*20 + cl] = v;
    float s = v, sq = v*v;
    s  += __shfl_xor(s,16);  s  += __shfl_xor(s,32);
    sq += __shfl_xor(sq,16); sq += __shfl_xor(sq,32);
    if (cg==0) { stS[w][j*20+cl]=s; stQ[w][j*20+cl]=sq; }
  }
  #pragma unroll
  for (int j=0;j<4;++j) {
    float v = acc1[j];                     // cols>=4 are exact 0 (zero pad)
    if (cl < 4) y[(size_t)(row0 + 4*cg + j)*20 + 16 + cl] = v;
    float s = v, sq = v*v;
    s  += __shfl_xor(s,16);  s  += __shfl_xor(s,32);
    sq += __shfl_xor(sq,16); sq += __shfl_xor(sq,32);
    if (cg==0 && cl<4) { stS[w][j*20+16+cl]=s; stQ[w][j*20+16+cl]=sq; }
  }
  __syncthreads();
  int slot = blockIdx.y*gridDim.x + blockIdx.x;
  if (t < 80) {
    stat[((size_t)slot*2+0)*CC + t] = stS[0][t]+stS[1][t]+stS[2][t]+stS[3][t];
  } else if (t < 160) {
    int c2 = t-80;
    stat[((size_t)slot*2+1)*CC + c2] = stQ[0][c2]+stQ[1][c2]+stQ[2][c2]+stQ[3][c2];
  }
}

// ---------------- f32 FMA Dirac fallback (only if ws too small for fp16 copies) ----------
template<typename AT> struct AFr;
template<> struct AFr<float> {
  float4 v;
  __device__ __forceinline__ void load(const float* p){ v = *(const float4*)p; }
  __device__ __forceinline__ float4 get() const { return v; }
};
template<int DR, typename AT>
__global__ __launch_bounds__(256) __attribute__((amdgpu_waves_per_eu(2,2)))
void k_dirac(
    const AT* __restrict__ A, const float* __restrict__ x,
    float* __restrict__ y, float* __restrict__ stat, int M, int K)
{
  static_assert(DR == 4, "stats channel mapping assumes DR==4");
  int b = blockIdx.y;
  A += (size_t)b*M*K; x += (size_t)b*(size_t)K*20; y += (size_t)b*(size_t)M*20;
  __shared__ float xs[2][20][256];
  __shared__ float stS[4][CC];
  __shared__ float stQ[4][CC];
  int t = threadIdx.x, lane = t & 63, w = t >> 6;
  int row0 = blockIdx.x*(4*DR) + w*DR;
  float acc[DR][20];
  #pragma unroll
  for (int r=0;r<DR;++r)
    #pragma unroll
    for (int q=0;q<20;++q) acc[r][q]=0.f;
  const float4* xv = (const float4*)x;
  int nchunk = K >> 8;
  const AT* Abase = A + (size_t)row0*K + (lane<<2);
  {
    float4 s0[5];
    #pragma unroll
    for (int i=0;i<5;++i) s0[i] = xv[(size_t)t*5 + i];
    #pragma unroll
    for (int i=0;i<5;++i) {
      xs[0][4*i+0][t]=s0[i].x; xs[0][4*i+1][t]=s0[i].y;
      xs[0][4*i+2][t]=s0[i].z; xs[0][4*i+3][t]=s0[i].w;
    }
  }
  AFr<AT> a[DR];
  #pragma unroll
  for (int r=0;r<DR;++r) a[r].load(Abase + (size_t)r*K);
  __syncthreads();
  for (int c=0; c<nchunk; ++c) {
    int cur = c & 1;
    bool more = (c+1 < nchunk);
    float4 st[5];
    if (more) {
      size_t kb = (size_t)(c+1)*256 + t;
      #pragma unroll
      for (int i=0;i<5;++i) st[i] = xv[kb*5 + i];
    }
    float4 af[DR];
    #pragma unroll
    for (int r=0;r<DR;++r) af[r] = a[r].get();
    if (more) {
      const AT* An = Abase + (size_t)(c+1)*256;
      #pragma unroll
      for (int r=0;r<DR;++r) a[r].load(An + (size_t)r*K);
    }
    #pragma unroll
    for (int q=0;q<20;++q) {
      float4 xq = *(const float4*)(&xs[cur][q][lane<<2]);
      #pragma unroll
      for (int r=0;r<DR;++r) {
        acc[r][q] = fmaf(af[r].x, xq.x, acc[r][q]);
        acc[r][q] = fmaf(af[r].y, xq.y, acc[r][q]);
        acc[r][q] = fmaf(af[r].z, xq.z, acc[r][q]);
        acc[r][q] = fmaf(af[r].w, xq.w, acc[r][q]);
      }
    }
    if (more) {
      #pragma unroll
      for (int i=0;i<5;++i) {
        xs[cur^1][4*i+0][t]=st[i].x; xs[cur^1][4*i+1][t]=st[i].y;
        xs[cur^1][4*i+2][t]=st[i].z; xs[cur^1][4*i+3][t]=st[i].w;
      }
    }
    __syncthreads();
  }
  #pragma unroll
  for (int r=0;r<DR;++r) {
    #pragma unroll
    for (int q=0;q<20;++q) {
      float s = acc[r][q];
      s += __shfl_xor(s, 1);  s += __shfl_xor(s, 2);
      s += __shfl_xor(s, 4);  s += __shfl_xor(s, 8);
      s += __shfl_xor(s, 16); s += __shfl_xor(s, 32);
      acc[r][q]=s;
    }
    if (lane==0) {
      float4* yp = (float4*)(y + (size_t)(row0+r)*20);
      yp[0] = make_float4(acc[r][0],acc[r][1],acc[r][2],acc[r][3]);
      yp[1] = make_float4(acc[r][4],acc[r][5],acc[r][6],acc[r][7]);
      yp[2] = make_float4(acc[r][8],acc[r][9],acc[r][10],acc[r][11]);
      yp[3] = make_float4(acc[r][12],acc[r][13],acc[r][14],acc[r][15]);
      yp[4] = make_float4(acc[r][16],acc[r][17],acc[r][18],acc[r][19]);
    }
  }
  if (lane == 0) {
    #pragma unroll
    for (int r=0;r<DR;++r)
      #pragma unroll
      for (int q=0;q<20;++q) {
        float v0 = acc[r][q];
        stS[w][r*20+q] = v0;
        stQ[w][r*20+q] = v0*v0;
      }
  }
  __syncthreads();
  int slot = blockIdx.y*gridDim.x + blockIdx.x;
  if (t < 80) {
    stat[((size_t)slot*2+0)*CC + t] = stS[0][t]+stS[1][t]+stS[2][t]+stS[3][t];
  } else if (t < 160) {
    int c2=t-80;
    stat[((size_t)slot*2+1)*CC + c2] = stQ[0][c2]+stQ[1][c2]+stQ[2][c2]+stQ[3][c2];
  }
}

// ---------------- fused BN(fold)+FC+ELU+residual, + output-stats partials ----------------
__global__ __launch_bounds__(256) void k_fc(
    const float* __restrict__ p1, const float* __restrict__ p2,
    const float* __restrict__ sp1, int ns1,
    const float* __restrict__ sp2, int ns2,
    const float* __restrict__ g, const float* __restrict__ bb,
    const float* __restrict__ W, const float* __restrict__ cb,
    const float* add, float* out,
    float* __restrict__ statout, int rows, float invrows)
{
  __shared__ float Wl[C2*CC];
  __shared__ float ad[2][C2];
  __shared__ float bpl[CC];
  __shared__ float xsh[3][C2];
  __shared__ float st[3][2][CC];
  int t = threadIdx.x;
  if (t < C2) {
    int c = (t<CC)? t : t-CC;
    const float* sp = (t<CC)? sp1 : sp2;
    int ns = (t<CC)? ns1 : ns2;
    float s=0.f,q=0.f;
    int i=0;
    for (; i+8<=ns; i+=8) {
      float vs[8], vq[8];
      #pragma unroll
      for (int j=0;j<8;++j){ vs[j]=sp[((i+j)*2+0)*CC+c]; vq[j]=sp[((i+j)*2+1)*CC+c]; }
      #pragma unroll
      for (int j=0;j<8;++j){ s+=vs[j]; q+=vq[j]; }
    }
    for (; i<ns; ++i){ s+=sp[(i*2+0)*CC+c]; q+=sp[(i*2+1)*CC+c]; }
    float mean = s*invrows;
    float var  = fmaf(-mean, mean, q*invrows);
    float aa   = g[t]*rsqrtf(var + 1e-5f);
    ad[0][t]=aa; ad[1][t]= bb[t] - mean*aa;
  }
  __syncthreads();
  for (int i=t;i<C2*CC;i+=256) Wl[i] = W[i]*ad[0][i/CC];
  if (t < CC) {
    float s = cb[t];
    for (int c2=0;c2<C2;c2+=8) {
      float wv[8];
      #pragma unroll
      for (int j=0;j<8;++j) wv[j] = W[(c2+j)*CC+t];
      #pragma unroll
      for (int j=0;j<8;++j) s = fmaf(ad[1][c2+j], wv[j], s);
    }
    bpl[t]=s;
  }
  __syncthreads();
  int c = t%CC, rs = t/CC;
  bool act = t < 240;
  float ssum=0.f, ssq=0.f;
  for (int r0 = blockIdx.x*3; r0 < rows; r0 += gridDim.x*3) {
    int row = r0 + rs;
    bool ok = act && row < rows;
    if (ok) {
      xsh[rs][c]    = p1[(size_t)row*CC+c];
      xsh[rs][CC+c] = p2[(size_t)row*CC+c];
    }
    __syncthreads();
    if (ok) {
      float acc = bpl[c];
      #pragma unroll 8
      for (int c2=0;c2<C2;++c2) acc = fmaf(xsh[rs][c2], Wl[c2*CC+c], acc);
      acc = acc>0.f ? acc : expm1f(acc);
      acc += add[(size_t)row*CC+c];
      out[(size_t)row*CC+c] = acc;
      ssum += acc; ssq = fmaf(acc,acc,ssq);
    }
    __syncthreads();
  }
  if (act){ st[rs][0][c]=ssum; st[rs][1][c]=ssq; }
  __syncthreads();
  if (t<CC){
    statout[(blockIdx.x*2+0)*CC+t] = st[0][0][t]+st[1][0][t]+st[2][0][t];
    statout[(blockIdx.x*2+1)*CC+t] = st[0][1][t]+st[1][1][t]+st[2][1][t];
  }
}

// ---------------- final: vf = elu(bn1(v2)+bn2(v1)+bn3(v0)) ----------------
__global__ __launch_bounds__(256) void k_final(
    const float* __restrict__ v2, const float* __restrict__ v1, const float* __restrict__ v0,
    const float* __restrict__ s2, const float* __restrict__ s1, const float* __restrict__ s0,
    const float* __restrict__ g1, const float* __restrict__ b1,
    const float* __restrict__ g2, const float* __restrict__ b2,
    const float* __restrict__ g3, const float* __restrict__ b3,
    float* __restrict__ vf)
{
  __shared__ float A[3][CC], D[3][CC];
  int t = threadIdx.x;
  if (t < 240) {
    int set = t/CC, c = t%CC;
    const float* sp  = set==0? s2 : (set==1? s1 : s0);
    const float* gg  = set==0? g1 : (set==1? g2 : g3);
    const float* bbp = set==0? b1 : (set==1? b2 : b3);
    float s=0.f,q=0.f;
    for (int i=0;i<256;i+=8){
      float vs[8], vq[8];
      #pragma unroll
      for (int j=0;j<8;++j){ vs[j]=sp[((i+j)*2+0)*CC+c]; vq[j]=sp[((i+j)*2+1)*CC+c]; }
      #pragma unroll
      for (int j=0;j<8;++j){ s+=vs[j]; q+=vq[j]; }
    }
    float mean = s*(1.f/ROWS_Y);
    float var  = fmaf(-mean,mean,q*(1.f/ROWS_Y));
    float aa   = gg[c]*rsqrtf(var+1e-5f);
    A[set][c]=aa; D[set][c]=bbp[c]-mean*aa;
  }
  __syncthreads();
  for (size_t idx = (size_t)blockIdx.x*256 + t; idx < (size_t)ROWS_Y*CC; idx += (size_t)gridDim.x*256) {
    int c = (int)(idx % CC);
    float val = fmaf(v2[idx],A[0][c],D[0][c]) + fmaf(v1[idx],A[1][c],D[1][c]) + fmaf(v0[idx],A[2][c],D[2][c]);
    vf[idx] = val>0.f? val : expm1f(val);
  }
}

// ---------------- w[b,n] = sum_k mask[b,k] L[b,k,n] ----------------
__global__ __launch_bounds__(256) void k_w(
    const float* __restrict__ mask, const float* __restrict__ L, float* __restrict__ w)
{
  int bx = blockIdx.x;            // 32
  int b = bx >> 4, n0 = (bx & 15) * 64;
  int t = threadIdx.x;
  int ks = t >> 6;
  __shared__ float red[4][64];
  float acc=0.f;
  const float* Lb = L + (size_t)b*NN*NN;
  const float* mb = mask + b*NN;
  int n = n0 + (t & 63);
  for (int k = ks*256; k < ks*256+256; k+=8) {
    float mv[8], lv[8];
    #pragma unroll
    for (int j=0;j<8;++j){ mv[j]=mb[k+j]; lv[j]=Lb[(size_t)(k+j)*NN + n]; }
    #pragma unroll
    for (int j=0;j<8;++j) acc = fmaf(mv[j], lv[j], acc);
  }
  red[ks][t&63]=acc;
  __syncthreads();
  if (t < 64) w[b*NN + n0 + t] = red[0][t]+red[1][t]+red[2][t]+red[3][t];
}

// ---------------- pooled partials: p1 = sum mask*vf, p2 = sum w*vf ----------------
__global__ __launch_bounds__(256) void k_pool(
    const float* __restrict__ vf, const float* __restrict__ mask,
    const float* __restrict__ w, float* __restrict__ part)
{
  int bx = blockIdx.x;            // 16
  int b = bx >> 3, slab = bx & 7;
  int t = threadIdx.x, c = t%CC, rs = t/CC;
  __shared__ float st[3][2][CC];
  if (t<240) {
    float a1=0.f,a2=0.f;
    for (int r = rs; r < 128; r += 3) {
      int row = slab*128 + r;
      float val = vf[((size_t)b*NN + row)*CC + c];
      a1 = fmaf(mask[b*NN+row], val, a1);
      a2 = fmaf(w[b*NN+row],    val, a2);
    }
    st[rs][0][c]=a1; st[rs][1][c]=a2;
  }
  __syncthreads();
  if (t<CC) {
    part[((b*8+slab)*2+0)*CC+t] = st[0][0][t]+st[1][0][t]+st[2][0][t];
    part[((b*8+slab)*2+1)*CC+t] = st[0][1][t]+st[1][1][t]+st[2][1][t];
  }
}

// ---------------- out[b,co] = (p1@W0 + p2@W1)/msum + b2 ----------------
__global__ __launch_bounds__(256) void k_out(
    const float* __restrict__ part, const float* __restrict__ mask,
    const float* __restrict__ W0, const float* __restrict__ W1,
    const float* __restrict__ b2, float* __restrict__ outp)
{
  __shared__ float pl[2][2][CC];
  __shared__ float msred[2][128];
  __shared__ float ms[2];
  int t = threadIdx.x;
  {
    int b = t >> 7, k0 = t & 127;
    float m[8];
    #pragma unroll
    for (int j=0;j<8;++j) m[j] = mask[b*NN + k0 + j*128];
    msred[b][k0] = ((m[0]+m[1])+(m[2]+m[3]))+((m[4]+m[5])+(m[6]+m[7]));
  }
  if (t < 160) {
    int b = t/CC, c = t%CC;
    float v1[8], v2[8];
    #pragma unroll
    for (int slab=0; slab<8; ++slab){
      v1[slab] = part[((b*8+slab)*2+0)*CC+c];
      v2[slab] = part[((b*8+slab)*2+1)*CC+c];
    }
    float s1=0.f,s2=0.f;
    #pragma unroll
    for (int slab=0;slab<8;++slab){ s1+=v1[slab]; s2+=v2[slab]; }
    pl[b][0][c]=s1; pl[b][1][c]=s2;
  }
  __syncthreads();
  if (t < 2) {
    float s=0.f;
    for (int k=0;k<128;++k) s += msred[t][k];
    ms[t]=s;
  }
  __syncthreads();
  int b = t >> 7, co = t & 127;
  float acc = 0.f;
  for (int c=0;c<CC;c+=8) {
    float w0[8], w1[8];
    #pragma unroll
    for (int j=0;j<8;++j){ w0[j]=W0[(c+j)*128+co]; w1[j]=W1[(c+j)*128+co]; }
    #pragma unroll
    for (int j=0;j<8;++j) acc += pl[b][0][c+j]*w0[j] + pl[b][1][c+j]*w1[j];
  }
  outp[t] = acc/ms[b] + b2[co];
}

extern "C" void kernel_launch(void* const* d_in, const int* in_sizes, int n_in,
                              void* d_out, int out_size, void* d_ws, size_t ws_size,
                              hipStream_t stream)
{
  const float* inp  = (const float*)d_in[0];
  const float* L    = (const float*)d_in[1];
  const float* Di   = (const float*)d_in[2];
  const float* DiA  = (const float*)d_in[3];
  const float* mask = (const float*)d_in[4];
  const float* c1W0 = (const float*)d_in[5];
  const float* c1W1 = (const float*)d_in[6];
  const float* c1b  = (const float*)d_in[7];
  const float* bn0g = (const float*)d_in[8];
  const float* bn0b = (const float*)d_in[9];
  const float* fc0W = (const float*)d_in[10];
  const float* fc0b = (const float*)d_in[11];
  const float* bn1g = (const float*)d_in[12];
  const float* bn1b = (const float*)d_in[13];
  const float* fc1W = (const float*)d_in[14];
  const float* fc1b = (const float*)d_in[15];
  const float* fbn1g= (const float*)d_in[16];
  const float* fbn1b= (const float*)d_in[17];
  const float* fbn2g= (const float*)d_in[18];
  const float* fbn2b= (const float*)d_in[19];
  const float* fbn3g= (const float*)d_in[20];
  const float* fbn3b= (const float*)d_in[21];
  const float* c2W0 = (const float*)d_in[22];
  const float* c2W1 = (const float*)d_in[23];
  const float* c2b  = (const float*)d_in[24];

  float* ws = (float*)d_ws;
  size_t off = 0;
  auto alloc = [&](size_t n)->float* { float* p = ws + off; off += (n + 63) & ~(size_t)63; return p; };
  const size_t STFL = (size_t)1024*2*CC;   // stat buffers: up to 1024 slots
  float* vb[3];   for (int i=0;i<3;++i) vb[i]   = alloc((size_t)BB*NN*CC);
  float* fb[2];   for (int i=0;i<2;++i) fb[i]   = alloc((size_t)BB*FF*CC);
  float* Dv       = alloc((size_t)BB*FF*CC);
  float* Df       = alloc((size_t)BB*NN*CC);
  float* vstat[3];for (int i=0;i<3;++i) vstat[i]= alloc(STFL);
  float* fstat[2];for (int i=0;i<2;++i) fstat[i]= alloc(STFL);
  float* dvstat   = alloc(STFL);
  float* dfstat   = alloc(STFL);
  float* vf       = alloc((size_t)BB*NN*CC);
  float* wv       = alloc((size_t)BB*NN);
  float* part     = alloc((size_t)16*2*CC);
  const size_t nDi = (size_t)BB*(4*FF)*(4*NN);      // 67,108,864 elems each
  _Float16* Dih  = (_Float16*)alloc(nDi/2);
  _Float16* DiAh = (_Float16*)alloc(nDi/2);
  bool usebf = (off*sizeof(float) <= ws_size);

  hipMemsetAsync(fb[0],    0, (size_t)BB*FF*CC*4, stream);
  hipMemsetAsync(fb[1],    0, (size_t)BB*FF*CC*4, stream);
  hipMemsetAsync(vb[1],    0, (size_t)BB*NN*CC*4, stream);
  hipMemsetAsync(fstat[0], 0, (size_t)256*2*CC*4, stream);

  if (usebf) {
    k_cvt<<<4096,256,0,stream>>>(Di,  (uint4*)Dih,  nDi/8);
    k_cvt<<<4096,256,0,stream>>>(DiA, (uint4*)DiAh, nDi/8);
  }

  k_conv1<<<128,256,0,stream>>>(inp, L, c1W0, c1W1, c1b, vb[0], vstat[0]);

  int nsDv = usebf ? 256 : 1024;
  int nsDf = usebf ? 128 : 512;
  int cur=0, p1=1, p2=2, fcur=0, fs=0;
  for (int it=0; it<NB_; ++it) {
    if (usebf) k_dirac_mfma<<<dim3(128,2),256,0,stream>>>(Dih, vb[cur], Dv, dvstat, 4*FF, 4*NN);
    else       k_dirac<4,float><<<dim3(512,2),256,0,stream>>>(Di, vb[cur], Dv, dvstat, 4*FF, 4*NN);
    k_fc<<<256,256,0,stream>>>(fb[fcur], Dv, fstat[fs],256, dvstat,nsDv,
        bn0g+(size_t)it*C2, bn0b+(size_t)it*C2, fc0W+(size_t)it*C2*CC, fc0b+(size_t)it*CC,
        fb[1-fcur], fb[1-fcur], fstat[1-fs], ROWS_X, 1.f/ROWS_X);
    fcur = 1-fcur; fs = 1-fs;
    if (usebf) k_dirac_mfma<<<dim3(64,2),256,0,stream>>>(DiAh, fb[fcur], Df, dfstat, 4*NN, 4*FF);
    else       k_dirac<4,float><<<dim3(256,2),256,0,stream>>>(DiA, fb[fcur], Df, dfstat, 4*NN, 4*FF);
    k_fc<<<256,256,0,stream>>>(vb[cur], Df, vstat[cur],(it==0?128:256), dfstat,nsDf,
        bn1g+(size_t)it*C2, bn1b+(size_t)it*C2, fc1W+(size_t)it*C2*CC, fc1b+(size_t)it*CC,
        vb[p1], vb[p2], vstat[p2], ROWS_Y, 1.f/ROWS_Y);
    int tmp=p2; p2=p1; p1=cur; cur=tmp;
  }

  k_final<<<128,256,0,stream>>>(vb[cur],vb[p1],vb[p2], vstat[cur],vstat[p1],vstat[p2],
      fbn1g,fbn1b,fbn2g,fbn2b,fbn3g,fbn3b, vf);
  k_w<<<32,256,0,stream>>>(mask, L, wv);
  k_pool<<<16,256,0,stream>>>(vf, mask, wv, part);
  k_out<<<1,256,0,stream>>>(part, mask, c2W0, c2W1, c2b, (float*)d_out);
}

// Round 10
// 2297.052 us; speedup vs baseline: 7.2981x; 1.1972x over previous
//
#include <hip/hip_runtime.h>
#include <cstdint>

#define BB 2
#define NN 1024
#define FF 2048
#define CC 80
#define C2 160
#define NB_ 15
#define ROWS_X (BB*FF)   /* 4096 */
#define ROWS_Y (BB*NN)   /* 2048 */

typedef __attribute__((ext_vector_type(8))) _Float16 half8;
typedef __attribute__((ext_vector_type(4))) float f32x4;

// ---------------- conv1: v = in@W0 + (L@in)@W1 + b, + v-stats (128 slots, float4-pair) ----------
__global__ __launch_bounds__(256) void k_conv1(
    const float* __restrict__ inp, const float* __restrict__ L,
    const float* __restrict__ W0, const float* __restrict__ W1,
    const float* __restrict__ bias, float* __restrict__ v,
    float4* __restrict__ vstat)
{
  int bx = blockIdx.x;            // 128 = 2 batches x 64 row-blocks
  int b = bx >> 6, rb = bx & 63;
  int row0 = rb * 16;
  __shared__ float red[256][3];
  __shared__ float lx[16][3];
  __shared__ float st[16][2][CC];
  int t = threadIdx.x;
  int rloc = t >> 4, sl = t & 15;
  const float* Lrow = L + ((size_t)b*NN + row0 + rloc) * NN;
  const float* ipb  = inp + (size_t)b*NN*3;
  float a0=0.f,a1=0.f,a2=0.f;
  for (int m = sl; m < NN; m += 16) {
    float lv = Lrow[m];
    a0 = fmaf(lv, ipb[m*3+0], a0);
    a1 = fmaf(lv, ipb[m*3+1], a1);
    a2 = fmaf(lv, ipb[m*3+2], a2);
  }
  red[t][0]=a0; red[t][1]=a1; red[t][2]=a2;
  __syncthreads();
  if (t < 48) {
    int row = t/3, ci = t%3;
    float s=0.f;
    for (int s2=0; s2<16; ++s2) s += red[row*16+s2][ci];
    lx[row][ci]=s;
  }
  __syncthreads();
  for (int o = t; o < 16*CC; o += 256) {
    int row = o/CC, c = o%CC;
    const float* ir = inp + ((size_t)b*NN + row0 + row)*3;
    float val = bias[c];
    #pragma unroll
    for (int ci=0; ci<3; ++ci)
      val += ir[ci]*W0[ci*CC+c] + lx[row][ci]*W1[ci*CC+c];
    v[((size_t)b*NN + row0 + row)*CC + c] = val;
    st[row][0][c] = val;
    st[row][1][c] = val*val;
  }
  __syncthreads();
  if (t < 40) {
    float s0=0.f,q0=0.f,s1=0.f,q1=0.f;
    for (int row=0; row<16; ++row){
      s0+=st[row][0][2*t];   q0+=st[row][1][2*t];
      s1+=st[row][0][2*t+1]; q1+=st[row][1][2*t+1];
    }
    vstat[(size_t)bx*40 + t] = make_float4(s0,q0,s1,q1);
  }
}

// ---------------- f32 -> fp16 (RNE) bulk convert ----------------
__device__ __forceinline__ unsigned pkh(float a, float b){
  _Float16 ha = (_Float16)a, hb = (_Float16)b;
  unsigned short ua = __builtin_bit_cast(unsigned short, ha);
  unsigned short ub = __builtin_bit_cast(unsigned short, hb);
  return (unsigned)ua | ((unsigned)ub << 16);
}
__global__ __launch_bounds__(256) void k_cvt(
    const float* __restrict__ src, uint4* __restrict__ dst, size_t n8)
{
  size_t i = (size_t)blockIdx.x*256 + threadIdx.x;
  size_t stride = (size_t)gridDim.x*256;
  for (; i < n8; i += stride) {
    const float4* s = (const float4*)src + i*2;
    float4 f0 = s[0], f1 = s[1];
    uint4 o;
    o.x = pkh(f0.x,f0.y); o.y = pkh(f0.z,f0.w);
    o.z = pkh(f1.x,f1.y); o.w = pkh(f1.z,f1.w);
    dst[i] = o;
  }
}

// ---------------- MFMA Dirac, K-split-2: y[M,20] = A[M,K](fp16) @ x[K,20] + stats ----------
// Block = 32 rows; wave w -> (row-tile rw = w&1, k-half kh = w>>1). Each wave:
// 16x16x32 MFMA over its K/2, acc combined via LDS (waves kh=1 -> kh=0).
// x staged per 256-k chunk per half into fp16 xT[buf][kh][32][264] (cols 20..31
// zero; +8 pad -> conflict-free ds_read_b128). A prefetched one chunk ahead.
// Stats: float4-pair layout stat[slot][40] = (S2p,Q2p,S2p+1,Q2p+1).
__global__ __launch_bounds__(256) __attribute__((amdgpu_waves_per_eu(2,2)))
void k_dirac_mfma(
    const _Float16* __restrict__ A, const float* __restrict__ x,
    float* __restrict__ y, float4* __restrict__ stat, int M, int K)
{
  int b = blockIdx.y;
  A += (size_t)b*M*K; x += (size_t)b*(size_t)K*20; y += (size_t)b*(size_t)M*20;
  __shared__ _Float16 xT[2][2][32][264];
  __shared__ float cb_[2][8][64];
  __shared__ float stS[2][CC], stQ[2][CC];
  int t = threadIdx.x, lane = t & 63, w = t >> 6;
  int rw = w & 1, kh = w >> 1;
  int row0 = blockIdx.x*32 + rw*16;
  int cl = lane & 15, cg = lane >> 4;
  int KH = K >> 1;
  f32x4 acc0 = {0.f,0.f,0.f,0.f}, acc1 = {0.f,0.f,0.f,0.f};
  const float4* xv = (const float4*)x;     // x row k = 5 float4s
  int nchunk = KH >> 8;
  const _Float16* Abase = A + (size_t)(row0 + cl)*K + (size_t)kh*KH + cg*8;

  // zero pad cols 20..31 of both buffers & halves (never re-touched)
  for (int i = t; i < 2*2*12*264; i += 256) {
    int bb = i / (2*12*264);
    int rem = i - bb*(2*12*264);
    int hh = rem / (12*264);
    int r2 = rem - hh*(12*264);
    xT[bb][hh][20 + r2/264][r2 % 264] = (_Float16)0.f;
  }
  { // stage chunk 0, both halves
    float4 s0[5], s1[5];
    #pragma unroll
    for (int i=0;i<5;++i){ s0[i]=xv[(size_t)t*5+i]; s1[i]=xv[((size_t)KH+t)*5+i]; }
    #pragma unroll
    for (int i=0;i<5;++i){
      xT[0][0][4*i+0][t]=(_Float16)s0[i].x; xT[0][0][4*i+1][t]=(_Float16)s0[i].y;
      xT[0][0][4*i+2][t]=(_Float16)s0[i].z; xT[0][0][4*i+3][t]=(_Float16)s0[i].w;
      xT[0][1][4*i+0][t]=(_Float16)s1[i].x; xT[0][1][4*i+1][t]=(_Float16)s1[i].y;
      xT[0][1][4*i+2][t]=(_Float16)s1[i].z; xT[0][1][4*i+3][t]=(_Float16)s1[i].w;
    }
  }
  half8 a_cur[8];
  #pragma unroll
  for (int ks=0;ks<8;++ks) a_cur[ks] = *(const half8*)(Abase + ks*32);
  __syncthreads();

  for (int c=0; c<nchunk; ++c) {
    int cur = c & 1;
    bool more = (c+1 < nchunk);
    float4 s0[5], s1[5];
    half8 a_nxt[8];
    if (more) {                            // issue next-chunk loads early
      size_t k0 = (size_t)(c+1)*256 + t;
      #pragma unroll
      for (int i=0;i<5;++i){ s0[i]=xv[k0*5+i]; s1[i]=xv[(k0+KH)*5+i]; }
      const _Float16* An = Abase + (size_t)(c+1)*256;
      #pragma unroll
      for (int ks=0;ks<8;++ks) a_nxt[ks] = *(const half8*)(An + ks*32);
    }
    #pragma unroll
    for (int ks=0;ks<8;++ks) {
      half8 b0 = *(const half8*)(&xT[cur][kh][cl     ][ks*32 + cg*8]);
      half8 b1 = *(const half8*)(&xT[cur][kh][16 + cl][ks*32 + cg*8]);
      acc0 = __builtin_amdgcn_mfma_f32_16x16x32_f16(a_cur[ks], b0, acc0, 0,0,0);
      acc1 = __builtin_amdgcn_mfma_f32_16x16x32_f16(a_cur[ks], b1, acc1, 0,0,0);
    }
    if (more) {                            // publish next buffer, rotate A
      #pragma unroll
      for (int i=0;i<5;++i){
        xT[cur^1][0][4*i+0][t]=(_Float16)s0[i].x; xT[cur^1][0][4*i+1][t]=(_Float16)s0[i].y;
        xT[cur^1][0][4*i+2][t]=(_Float16)s0[i].z; xT[cur^1][0][4*i+3][t]=(_Float16)s0[i].w;
        xT[cur^1][1][4*i+0][t]=(_Float16)s1[i].x; xT[cur^1][1][4*i+1][t]=(_Float16)s1[i].y;
        xT[cur^1][1][4*i+2][t]=(_Float16)s1[i].z; xT[cur^1][1][4*i+3][t]=(_Float16)s1[i].w;
      }
      #pragma unroll
      for (int ks=0;ks<8;++ks) a_cur[ks] = a_nxt[ks];
    }
    __syncthreads();
  }

  // combine k-halves: waves kh=1 publish, kh=0 accumulate
  if (kh == 1) {
    #pragma unroll
    for (int j=0;j<4;++j){ cb_[rw][j][lane]=acc0[j]; cb_[rw][4+j][lane]=acc1[j]; }
  }
  __syncthreads();
  if (kh == 0) {
    #pragma unroll
    for (int j=0;j<4;++j){ acc0[j]+=cb_[rw][j][lane]; acc1[j]+=cb_[rw][4+j][lane]; }
    // y-write + stats. D: row = row0+4*cg+j, col = cl (tile0) / 16+cl (tile1, cl<4)
    #pragma unroll
    for (int j=0;j<4;++j) {
      float v = acc0[j];
      y[(size_t)(row0 + 4*cg + j)*20 + cl] = v;
      float s = v, sq = v*v;
      s  += __shfl_xor(s,16);  s  += __shfl_xor(s,32);
      sq += __shfl_xor(sq,16); sq += __shfl_xor(sq,32);
      if (cg==0) { stS[rw][j*20+cl]=s; stQ[rw][j*20+cl]=sq; }
    }
    #pragma unroll
    for (int j=0;j<4;++j) {
      float v = acc1[j];                   // cols>=4 exact 0 (zero pad)
      if (cl < 4) y[(size_t)(row0 + 4*cg + j)*20 + 16 + cl] = v;
      float s = v, sq = v*v;
      s  += __shfl_xor(s,16);  s  += __shfl_xor(s,32);
      sq += __shfl_xor(sq,16); sq += __shfl_xor(sq,32);
      if (cg==0 && cl<4) { stS[rw][j*20+16+cl]=s; stQ[rw][j*20+16+cl]=sq; }
    }
  }
  __syncthreads();
  int slot = blockIdx.y*gridDim.x + blockIdx.x;
  if (t < 40) {
    float4 o;
    o.x = stS[0][2*t]  +stS[1][2*t];
    o.y = stQ[0][2*t]  +stQ[1][2*t];
    o.z = stS[0][2*t+1]+stS[1][2*t+1];
    o.w = stQ[0][2*t+1]+stQ[1][2*t+1];
    stat[(size_t)slot*40 + t] = o;
  }
}

// ---------------- f32 FMA Dirac fallback (ws too small) ----------------
__global__ __launch_bounds__(256) __attribute__((amdgpu_waves_per_eu(2,2)))
void k_dirac_f32(
    const float* __restrict__ A, const float* __restrict__ x,
    float* __restrict__ y, float4* __restrict__ stat, int M, int K)
{
  const int DR = 4;
  int b = blockIdx.y;
  A += (size_t)b*M*K; x += (size_t)b*(size_t)K*20; y += (size_t)b*(size_t)M*20;
  __shared__ float xs[2][20][256];
  __shared__ float stS[4][CC], stQ[4][CC];
  int t = threadIdx.x, lane = t & 63, w = t >> 6;
  int row0 = blockIdx.x*(4*DR) + w*DR;
  float acc[DR][20];
  #pragma unroll
  for (int r=0;r<DR;++r)
    #pragma unroll
    for (int q=0;q<20;++q) acc[r][q]=0.f;
  const float4* xv = (const float4*)x;
  int nchunk = K >> 8;
  const float* Abase = A + (size_t)row0*K + (lane<<2);
  {
    float4 s0[5];
    #pragma unroll
    for (int i=0;i<5;++i) s0[i] = xv[(size_t)t*5 + i];
    #pragma unroll
    for (int i=0;i<5;++i) {
      xs[0][4*i+0][t]=s0[i].x; xs[0][4*i+1][t]=s0[i].y;
      xs[0][4*i+2][t]=s0[i].z; xs[0][4*i+3][t]=s0[i].w;
    }
  }
  float4 a[DR];
  #pragma unroll
  for (int r=0;r<DR;++r) a[r] = *(const float4*)(Abase + (size_t)r*K);
  __syncthreads();
  for (int c=0; c<nchunk; ++c) {
    int cur = c & 1;
    bool more = (c+1 < nchunk);
    float4 st[5];
    if (more) {
      size_t kb = (size_t)(c+1)*256 + t;
      #pragma unroll
      for (int i=0;i<5;++i) st[i] = xv[kb*5 + i];
    }
    float4 af[DR];
    #pragma unroll
    for (int r=0;r<DR;++r) af[r] = a[r];
    if (more) {
      const float* An = Abase + (size_t)(c+1)*256;
      #pragma unroll
      for (int r=0;r<DR;++r) a[r] = *(const float4*)(An + (size_t)r*K);
    }
    #pragma unroll
    for (int q=0;q<20;++q) {
      float4 xq = *(const float4*)(&xs[cur][q][lane<<2]);
      #pragma unroll
      for (int r=0;r<DR;++r) {
        acc[r][q] = fmaf(af[r].x, xq.x, acc[r][q]);
        acc[r][q] = fmaf(af[r].y, xq.y, acc[r][q]);
        acc[r][q] = fmaf(af[r].z, xq.z, acc[r][q]);
        acc[r][q] = fmaf(af[r].w, xq.w, acc[r][q]);
      }
    }
    if (more) {
      #pragma unroll
      for (int i=0;i<5;++i) {
        xs[cur^1][4*i+0][t]=st[i].x; xs[cur^1][4*i+1][t]=st[i].y;
        xs[cur^1][4*i+2][t]=st[i].z; xs[cur^1][4*i+3][t]=st[i].w;
      }
    }
    __syncthreads();
  }
  #pragma unroll
  for (int r=0;r<DR;++r) {
    #pragma unroll
    for (int q=0;q<20;++q) {
      float s = acc[r][q];
      s += __shfl_xor(s, 1);  s += __shfl_xor(s, 2);
      s += __shfl_xor(s, 4);  s += __shfl_xor(s, 8);
      s += __shfl_xor(s, 16); s += __shfl_xor(s, 32);
      acc[r][q]=s;
    }
    if (lane==0) {
      float4* yp = (float4*)(y + (size_t)(row0+r)*20);
      yp[0] = make_float4(acc[r][0],acc[r][1],acc[r][2],acc[r][3]);
      yp[1] = make_float4(acc[r][4],acc[r][5],acc[r][6],acc[r][7]);
      yp[2] = make_float4(acc[r][8],acc[r][9],acc[r][10],acc[r][11]);
      yp[3] = make_float4(acc[r][12],acc[r][13],acc[r][14],acc[r][15]);
      yp[4] = make_float4(acc[r][16],acc[r][17],acc[r][18],acc[r][19]);
    }
  }
  if (lane == 0) {
    #pragma unroll
    for (int r=0;r<DR;++r)
      #pragma unroll
      for (int q=0;q<20;++q) {
        float v0 = acc[r][q];
        stS[w][r*20+q] = v0;
        stQ[w][r*20+q] = v0*v0;
      }
  }
  __syncthreads();
  int slot = blockIdx.y*gridDim.x + blockIdx.x;
  if (t < 40) {
    float4 o;
    o.x = stS[0][2*t]+stS[1][2*t]+stS[2][2*t]+stS[3][2*t];
    o.y = stQ[0][2*t]+stQ[1][2*t]+stQ[2][2*t]+stQ[3][2*t];
    o.z = stS[0][2*t+1]+stS[1][2*t+1]+stS[2][2*t+1]+stS[3][2*t+1];
    o.w = stQ[0][2*t+1]+stQ[1][2*t+1]+stQ[2][2*t+1]+stQ[3][2*t+1];
    stat[(size_t)slot*40 + t] = o;
  }
}

// ---------------- fused BN(fold)+FC+ELU+residual + float4-pair stats ----------------
__global__ __launch_bounds__(256) void k_fc(
    const float* __restrict__ p1, const float* __restrict__ p2,
    const float4* __restrict__ sp1, int ns1,
    const float4* __restrict__ sp2, int ns2,
    const float* __restrict__ g, const float* __restrict__ bb,
    const float* __restrict__ W, const float* __restrict__ cb,
    const float* add, float* out,
    float4* __restrict__ statout, int rows, float invrows)
{
  __shared__ float Wl[C2*CC];
  __shared__ float ad[2][C2];
  __shared__ float bpl[CC];
  __shared__ float xsh[3][C2];
  __shared__ float st[3][2][CC];
  __shared__ float4 pst[2][2][40];
  int t = threadIdx.x;
  // parallel stats reduce: 160 tasks = (half h, src s, pair p)
  if (t < 160) {
    int p = t % 40, s = (t/40) & 1, h = t/80;
    const float4* sp = s ? sp2 : sp1;
    int ns = s ? ns2 : ns1;
    int half = ns >> 1;
    const float4* base = sp + (size_t)(h*half)*40 + p;
    float4 acc = {0.f,0.f,0.f,0.f};
    for (int i=0;i<half;i+=8) {
      float4 v[8];
      #pragma unroll
      for (int j=0;j<8;++j) v[j] = base[(size_t)(i+j)*40];
      #pragma unroll
      for (int j=0;j<8;++j){ acc.x+=v[j].x; acc.y+=v[j].y; acc.z+=v[j].z; acc.w+=v[j].w; }
    }
    pst[h][s][p] = acc;
  }
  __syncthreads();
  if (t < C2) {
    int s = (t < CC) ? 0 : 1;
    int chl = (t < CC) ? t : t - CC;
    int p = chl >> 1, e = chl & 1;
    float4 a0 = pst[0][s][p], a1 = pst[1][s][p];
    float S = e ? (a0.z + a1.z) : (a0.x + a1.x);
    float Q = e ? (a0.w + a1.w) : (a0.y + a1.y);
    float mean = S*invrows;
    float var  = fmaf(-mean, mean, Q*invrows);
    float aa   = g[t]*rsqrtf(var + 1e-5f);
    ad[0][t]=aa; ad[1][t]= bb[t] - mean*aa;
  }
  __syncthreads();
  for (int i=t;i<C2*CC;i+=256) Wl[i] = W[i]*ad[0][i/CC];
  if (t < CC) {
    float s = cb[t];
    for (int c2=0;c2<C2;c2+=8) {
      float wv[8];
      #pragma unroll
      for (int j=0;j<8;++j) wv[j] = W[(c2+j)*CC+t];
      #pragma unroll
      for (int j=0;j<8;++j) s = fmaf(ad[1][c2+j], wv[j], s);
    }
    bpl[t]=s;
  }
  __syncthreads();
  int c = t%CC, rs = t/CC;
  bool act = t < 240;
  float ssum=0.f, ssq=0.f;
  for (int r0 = blockIdx.x*3; r0 < rows; r0 += gridDim.x*3) {
    int row = r0 + rs;
    bool ok = act && row < rows;
    if (ok) {
      xsh[rs][c]    = p1[(size_t)row*CC+c];
      xsh[rs][CC+c] = p2[(size_t)row*CC+c];
    }
    __syncthreads();
    if (ok) {
      float acc = bpl[c];
      #pragma unroll 8
      for (int c2=0;c2<C2;++c2) acc = fmaf(xsh[rs][c2], Wl[c2*CC+c], acc);
      acc = acc>0.f ? acc : expm1f(acc);
      acc += add[(size_t)row*CC+c];
      out[(size_t)row*CC+c] = acc;
      ssum += acc; ssq = fmaf(acc,acc,ssq);
    }
    __syncthreads();
  }
  if (act){ st[rs][0][c]=ssum; st[rs][1][c]=ssq; }
  __syncthreads();
  if (t < 40) {
    float4 o;
    o.x = st[0][0][2*t]  +st[1][0][2*t]  +st[2][0][2*t];
    o.y = st[0][1][2*t]  +st[1][1][2*t]  +st[2][1][2*t];
    o.z = st[0][0][2*t+1]+st[1][0][2*t+1]+st[2][0][2*t+1];
    o.w = st[0][1][2*t+1]+st[1][1][2*t+1]+st[2][1][2*t+1];
    statout[(size_t)blockIdx.x*40 + t] = o;
  }
}

// ---------------- final: vf = elu(bn1(v2)+bn2(v1)+bn3(v0)) ----------------
__global__ __launch_bounds__(256) void k_final(
    const float* __restrict__ v2, const float* __restrict__ v1, const float* __restrict__ v0,
    const float4* __restrict__ s2, const float4* __restrict__ s1, const float4* __restrict__ s0,
    const float* __restrict__ g1, const float* __restrict__ b1,
    const float* __restrict__ g2, const float* __restrict__ b2,
    const float* __restrict__ g3, const float* __restrict__ b3,
    float* __restrict__ vf, int ns)
{
  __shared__ float A[3][CC], D[3][CC];
  __shared__ float4 pf[2][3][40];
  int t = threadIdx.x;
  if (t < 240) {
    int p = t % 40, s = (t/40) % 3, h = t/120;
    const float4* sp = s==0 ? s2 : (s==1 ? s1 : s0);
    int half = ns >> 1;
    const float4* base = sp + (size_t)(h*half)*40 + p;
    float4 acc = {0.f,0.f,0.f,0.f};
    for (int i=0;i<half;i+=8) {
      float4 v[8];
      #pragma unroll
      for (int j=0;j<8;++j) v[j] = base[(size_t)(i+j)*40];
      #pragma unroll
      for (int j=0;j<8;++j){ acc.x+=v[j].x; acc.y+=v[j].y; acc.z+=v[j].z; acc.w+=v[j].w; }
    }
    pf[h][s][p] = acc;
  }
  __syncthreads();
  if (t < 240) {
    int set = t/80, chl = t%80, p = chl>>1, e = chl&1;
    const float* gg  = set==0? g1 : (set==1? g2 : g3);
    const float* bbp = set==0? b1 : (set==1? b2 : b3);
    float4 a0 = pf[0][set][p], a1 = pf[1][set][p];
    float S = e ? (a0.z + a1.z) : (a0.x + a1.x);
    float Q = e ? (a0.w + a1.w) : (a0.y + a1.y);
    float mean = S*(1.f/ROWS_Y);
    float var  = fmaf(-mean,mean,Q*(1.f/ROWS_Y));
    float aa   = gg[chl]*rsqrtf(var+1e-5f);
    A[set][chl]=aa; D[set][chl]=bbp[chl]-mean*aa;
  }
  __syncthreads();
  for (size_t idx = (size_t)blockIdx.x*256 + t; idx < (size_t)ROWS_Y*CC; idx += (size_t)gridDim.x*256) {
    int c = (int)(idx % CC);
    float val = fmaf(v2[idx],A[0][c],D[0][c]) + fmaf(v1[idx],A[1][c],D[1][c]) + fmaf(v0[idx],A[2][c],D[2][c]);
    vf[idx] = val>0.f? val : expm1f(val);
  }
}

// ---------------- w[b,n] = sum_k mask[b,k] L[b,k,n] ----------------
__global__ __launch_bounds__(256) void k_w(
    const float* __restrict__ mask, const float* __restrict__ L, float* __restrict__ w)
{
  int bx = blockIdx.x;            // 32
  int b = bx >> 4, n0 = (bx & 15) * 64;
  int t = threadIdx.x;
  int ks = t >> 6;
  __shared__ float red[4][64];
  float acc=0.f;
  const float* Lb = L + (size_t)b*NN*NN;
  const float* mb = mask + b*NN;
  int n = n0 + (t & 63);
  for (int k = ks*256; k < ks*256+256; k+=8) {
    float mv[8], lv[8];
    #pragma unroll
    for (int j=0;j<8;++j){ mv[j]=mb[k+j]; lv[j]=Lb[(size_t)(k+j)*NN + n]; }
    #pragma unroll
    for (int j=0;j<8;++j) acc = fmaf(mv[j], lv[j], acc);
  }
  red[ks][t&63]=acc;
  __syncthreads();
  if (t < 64) w[b*NN + n0 + t] = red[0][t]+red[1][t]+red[2][t]+red[3][t];
}

// ---------------- pooled partials: p1 = sum mask*vf, p2 = sum w*vf ----------------
__global__ __launch_bounds__(256) void k_pool(
    const float* __restrict__ vf, const float* __restrict__ mask,
    const float* __restrict__ w, float* __restrict__ part)
{
  int bx = blockIdx.x;            // 16
  int b = bx >> 3, slab = bx & 7;
  int t = threadIdx.x, c = t%CC, rs = t/CC;
  __shared__ float st[3][2][CC];
  if (t<240) {
    float a1=0.f,a2=0.f;
    for (int r = rs; r < 128; r += 3) {
      int row = slab*128 + r;
      float val = vf[((size_t)b*NN + row)*CC + c];
      a1 = fmaf(mask[b*NN+row], val, a1);
      a2 = fmaf(w[b*NN+row],    val, a2);
    }
    st[rs][0][c]=a1; st[rs][1][c]=a2;
  }
  __syncthreads();
  if (t<CC) {
    part[((b*8+slab)*2+0)*CC+t] = st[0][0][t]+st[1][0][t]+st[2][0][t];
    part[((b*8+slab)*2+1)*CC+t] = st[0][1][t]+st[1][1][t]+st[2][1][t];
  }
}

// ---------------- out[b,co] = (p1@W0 + p2@W1)/msum + b2 ----------------
__global__ __launch_bounds__(256) void k_out(
    const float* __restrict__ part, const float* __restrict__ mask,
    const float* __restrict__ W0, const float* __restrict__ W1,
    const float* __restrict__ b2, float* __restrict__ outp)
{
  __shared__ float pl[2][2][CC];
  __shared__ float msred[2][128];
  __shared__ float ms[2];
  int t = threadIdx.x;
  {
    int b = t >> 7, k0 = t & 127;
    float m[8];
    #pragma unroll
    for (int j=0;j<8;++j) m[j] = mask[b*NN + k0 + j*128];
    msred[b][k0] = ((m[0]+m[1])+(m[2]+m[3]))+((m[4]+m[5])+(m[6]+m[7]));
  }
  if (t < 160) {
    int b = t/CC, c = t%CC;
    float v1[8], v2[8];
    #pragma unroll
    for (int slab=0; slab<8; ++slab){
      v1[slab] = part[((b*8+slab)*2+0)*CC+c];
      v2[slab] = part[((b*8+slab)*2+1)*CC+c];
    }
    float s1=0.f,s2=0.f;
    #pragma unroll
    for (int slab=0;slab<8;++slab){ s1+=v1[slab]; s2+=v2[slab]; }
    pl[b][0][c]=s1; pl[b][1][c]=s2;
  }
  __syncthreads();
  if (t < 2) {
    float s=0.f;
    for (int k=0;k<128;++k) s += msred[t][k];
    ms[t]=s;
  }
  __syncthreads();
  int b = t >> 7, co = t & 127;
  float acc = 0.f;
  for (int c=0;c<CC;c+=8) {
    float w0[8], w1[8];
    #pragma unroll
    for (int j=0;j<8;++j){ w0[j]=W0[(c+j)*128+co]; w1[j]=W1[(c+j)*128+co]; }
    #pragma unroll
    for (int j=0;j<8;++j) acc += pl[b][0][c+j]*w0[j] + pl[b][1][c+j]*w1[j];
  }
  outp[t] = acc/ms[b] + b2[co];
}

extern "C" void kernel_launch(void* const* d_in, const int* in_sizes, int n_in,
                              void* d_out, int out_size, void* d_ws, size_t ws_size,
                              hipStream_t stream)
{
  const float* inp  = (const float*)d_in[0];
  const float* L    = (const float*)d_in[1];
  const float* Di   = (const float*)d_in[2];
  const float* DiA  = (const float*)d_in[3];
  const float* mask = (const float*)d_in[4];
  const float* c1W0 = (const float*)d_in[5];
  const float* c1W1 = (const float*)d_in[6];
  const float* c1b  = (const float*)d_in[7];
  const float* bn0g = (const float*)d_in[8];
  const float* bn0b = (const float*)d_in[9];
  const float* fc0W = (const float*)d_in[10];
  const float* fc0b = (const float*)d_in[11];
  const float* bn1g = (const float*)d_in[12];
  const float* bn1b = (const float*)d_in[13];
  const float* fc1W = (const float*)d_in[14];
  const float* fc1b = (const float*)d_in[15];
  const float* fbn1g= (const float*)d_in[16];
  const float* fbn1b= (const float*)d_in[17];
  const float* fbn2g= (const float*)d_in[18];
  const float* fbn2b= (const float*)d_in[19];
  const float* fbn3g= (const float*)d_in[20];
  const float* fbn3b= (const float*)d_in[21];
  const float* c2W0 = (const float*)d_in[22];
  const float* c2W1 = (const float*)d_in[23];
  const float* c2b  = (const float*)d_in[24];

  float* ws = (float*)d_ws;
  size_t off = 0;
  auto alloc = [&](size_t n)->float* { float* p = ws + off; off += (n + 63) & ~(size_t)63; return p; };
  const size_t STFL = (size_t)1024*40*4;   // stat buffer: up to 1024 slots x 40 float4
  float* vb[3];   for (int i=0;i<3;++i) vb[i]   = alloc((size_t)BB*NN*CC);
  float* fb[2];   for (int i=0;i<2;++i) fb[i]   = alloc((size_t)BB*FF*CC);
  float* Dv       = alloc((size_t)BB*FF*CC);
  float* Df       = alloc((size_t)BB*NN*CC);
  float4* vstat[3];for (int i=0;i<3;++i) vstat[i]= (float4*)alloc(STFL);
  float4* fstat[2];for (int i=0;i<2;++i) fstat[i]= (float4*)alloc(STFL);
  float4* dvstat  = (float4*)alloc(STFL);
  float4* dfstat  = (float4*)alloc(STFL);
  float* vf       = alloc((size_t)BB*NN*CC);
  float* wv       = alloc((size_t)BB*NN);
  float* part     = alloc((size_t)16*2*CC);
  const size_t nDi = (size_t)BB*(4*FF)*(4*NN);      // 67,108,864 elems each
  _Float16* Dih  = (_Float16*)alloc(nDi/2);
  _Float16* DiAh = (_Float16*)alloc(nDi/2);
  bool usebf = (off*sizeof(float) <= ws_size);

  hipMemsetAsync(fb[0],    0, (size_t)BB*FF*CC*4, stream);
  hipMemsetAsync(fb[1],    0, (size_t)BB*FF*CC*4, stream);
  hipMemsetAsync(vb[1],    0, (size_t)BB*NN*CC*4, stream);
  hipMemsetAsync(fstat[0], 0, (size_t)256*40*16, stream);

  if (usebf) {
    k_cvt<<<4096,256,0,stream>>>(Di,  (uint4*)Dih,  nDi/8);
    k_cvt<<<4096,256,0,stream>>>(DiA, (uint4*)DiAh, nDi/8);
  }

  k_conv1<<<128,256,0,stream>>>(inp, L, c1W0, c1W1, c1b, vb[0], vstat[0]);

  int nsDv = usebf ? 512 : 1024;   // Di-dirac slots
  int nsDf = usebf ? 256 : 512;    // DiA-dirac slots
  int cur=0, p1=1, p2=2, fcur=0, fs=0;
  for (int it=0; it<NB_; ++it) {
    if (usebf) k_dirac_mfma<<<dim3(256,2),256,0,stream>>>(Dih, vb[cur], Dv, dvstat, 4*FF, 4*NN);
    else       k_dirac_f32 <<<dim3(512,2),256,0,stream>>>(Di,  vb[cur], Dv, dvstat, 4*FF, 4*NN);
    k_fc<<<256,256,0,stream>>>(fb[fcur], Dv, fstat[fs],256, dvstat,nsDv,
        bn0g+(size_t)it*C2, bn0b+(size_t)it*C2, fc0W+(size_t)it*C2*CC, fc0b+(size_t)it*CC,
        fb[1-fcur], fb[1-fcur], fstat[1-fs], ROWS_X, 1.f/ROWS_X);
    fcur = 1-fcur; fs = 1-fs;
    if (usebf) k_dirac_mfma<<<dim3(128,2),256,0,stream>>>(DiAh, fb[fcur], Df, dfstat, 4*NN, 4*FF);
    else       k_dirac_f32 <<<dim3(256,2),256,0,stream>>>(DiA,  fb[fcur], Df, dfstat, 4*NN, 4*FF);
    k_fc<<<256,256,0,stream>>>(vb[cur], Df, vstat[cur],(it==0?128:256), dfstat,nsDf,
        bn1g+(size_t)it*C2, bn1b+(size_t)it*C2, fc1W+(size_t)it*C2*CC, fc1b+(size_t)it*CC,
        vb[p1], vb[p2], vstat[p2], ROWS_Y, 1.f/ROWS_Y);
    int tmp=p2; p2=p1; p1=cur; cur=tmp;
  }

  k_final<<<128,256,0,stream>>>(vb[cur],vb[p1],vb[p2], vstat[cur],vstat[p1],vstat[p2],
      fbn1g,fbn1b,fbn2g,fbn2b,fbn3g,fbn3b, vf, 256);
  k_w<<<32,256,0,stream>>>(mask, L, wv);
  k_pool<<<16,256,0,stream>>>(vf, mask, wv, part);
  k_out<<<1,256,0,stream>>>(part, mask, c2W0, c2W1, c2b, (float*)d_out);
}